// Round 1
// baseline (3011.747 us; speedup 1.0000x reference)
//
#include <hip/hip_runtime.h>
#include <math.h>

#define WG 256

__device__ __forceinline__ float gelu_f(float x) {
    // jax.nn.gelu approximate=False: 0.5*x*(1+erf(x/sqrt(2)))
    return 0.5f * x * (1.0f + erff(x * 0.7071067811865476f));
}

// -------------------- Kernel 1: per-edge MLP + scatter --------------------
__global__ __launch_bounds__(WG) void edge_kernel(
    const float* __restrict__ coords,
    const float* __restrict__ normals,
    const float* __restrict__ curv,
    const int*   __restrict__ eidx,
    const float* __restrict__ W1, const float* __restrict__ b1,
    const float* __restrict__ W2, const float* __restrict__ b2,
    const float* __restrict__ W3, const float* __restrict__ b3,
    float* __restrict__ S, float* __restrict__ deg,
    float* __restrict__ stats,   // [0:16) sum(ef), [16:32) sum(ef^2)
    int E)
{
    __shared__ float sW1[512];    // [8][64]
    __shared__ float sW2[2048];   // [64][32]
    __shared__ float sW3[512];    // [32][16]
    __shared__ float sB1[64];
    __shared__ float sB2[32];
    __shared__ float sB3[16];
    __shared__ float red[4][32];

    const int t = threadIdx.x;
    for (int i = t; i < 512;  i += WG) sW1[i] = W1[i];
    for (int i = t; i < 2048; i += WG) sW2[i] = W2[i];
    for (int i = t; i < 512;  i += WG) sW3[i] = W3[i];
    if (t < 64) sB1[t] = b1[t];
    if (t < 32) sB2[t] = b2[t];
    if (t < 16) sB3[t] = b3[t];
    __syncthreads();

    float vsum[16], vsq[16];
#pragma unroll
    for (int k = 0; k < 16; ++k) { vsum[k] = 0.f; vsq[k] = 0.f; }

    const int stride = gridDim.x * WG;
    for (int e = blockIdx.x * WG + t; e < E; e += stride) {
        const int r = eidx[e];
        const int c = eidx[E + e];

        const float rx = coords[3*r], ry = coords[3*r+1], rz = coords[3*r+2];
        const float cx = coords[3*c], cy = coords[3*c+1], cz = coords[3*c+2];
        const float dx = cx - rx, dy = cy - ry, dz = cz - rz;
        const float nrx = normals[3*r], nry = normals[3*r+1], nrz = normals[3*r+2];
        const float ncx = normals[3*c], ncy = normals[3*c+1], ncz = normals[3*c+2];

        const float ndot = nrx*ncx + nry*ncy + nrz*ncz;
        const float dn   = sqrtf(dx*dx + dy*dy + dz*dz) + 1e-8f;
        const float inv  = 1.0f / dn;
        const float lo = -1.0f + 1e-8f, hi = 1.0f - 1e-8f;
        const float cr = fminf(fmaxf((nrx*dx + nry*dy + nrz*dz) * inv, lo), hi);
        const float cc = fminf(fmaxf((ncx*dx + ncy*dy + ncz*dz) * inv, lo), hi);
        const float cd0 = curv[4*c]   - curv[4*r];
        const float cd1 = curv[4*c+1] - curv[4*r+1];

        const float f[8] = {dx, dy, dz, ndot, cr, cc, cd0, cd1};

        // Layer1+2 fused: never materialize h1[64] as an array.
        float acc2[32];
#pragma unroll
        for (int j = 0; j < 32; ++j) acc2[j] = sB2[j];
        for (int i = 0; i < 64; ++i) {
            float a = sB1[i];
#pragma unroll
            for (int k = 0; k < 8; ++k) a += f[k] * sW1[k*64 + i];
            const float g = gelu_f(a);
#pragma unroll
            for (int j = 0; j < 32; ++j) acc2[j] += g * sW2[i*32 + j];
        }
        // Layer 3 (unrolled so acc2 stays in registers)
        float ef[16];
#pragma unroll
        for (int k = 0; k < 16; ++k) ef[k] = sB3[k];
#pragma unroll
        for (int i = 0; i < 32; ++i) {
            const float g = gelu_f(acc2[i]);
#pragma unroll
            for (int k = 0; k < 16; ++k) ef[k] += g * sW3[i*16 + k];
        }

        // scatter raw ef; BN affine is applied later per-node:
        // sum(a*ef+b over incident) = a*S + b*deg
#pragma unroll
        for (int k = 0; k < 16; ++k) {
            atomicAdd(&S[16*(size_t)r + k], ef[k]);
            atomicAdd(&S[16*(size_t)c + k], ef[k]);
            vsum[k] += ef[k];
            vsq[k]  += ef[k] * ef[k];
        }
        atomicAdd(&deg[r], 1.0f);
        atomicAdd(&deg[c], 1.0f);
    }

    // block reduction of BN stats
#pragma unroll
    for (int k = 0; k < 16; ++k) {
        float a = vsum[k], b = vsq[k];
#pragma unroll
        for (int off = 32; off > 0; off >>= 1) {
            a += __shfl_down(a, off);
            b += __shfl_down(b, off);
        }
        vsum[k] = a; vsq[k] = b;
    }
    const int wave = t >> 6;
    if ((t & 63) == 0) {
#pragma unroll
        for (int k = 0; k < 16; ++k) {
            red[wave][k]      = vsum[k];
            red[wave][16 + k] = vsq[k];
        }
    }
    __syncthreads();
    if (t < 32) {
        const float s = red[0][t] + red[1][t] + red[2][t] + red[3][t];
        atomicAdd(&stats[t], s);
    }
}

// ---------- Kernel 2: per-node normalize + project + node-BN stats ----------
__global__ __launch_bounds__(WG) void node_kernel(
    const float* __restrict__ S, const float* __restrict__ deg,
    const float* __restrict__ Wp, const float* __restrict__ bp,
    const float* __restrict__ gE, const float* __restrict__ bE,
    float* __restrict__ X, float* __restrict__ stats,
    int N, float invE)
{
    __shared__ float sWp[256];
    __shared__ float sBp[16];
    __shared__ float sA[16], sB[16];
    __shared__ float red[4][32];

    const int t = threadIdx.x;
    sWp[t] = Wp[t & 255];   // WG==256 so every slot covered
    if (t < 16) {
        sBp[t] = bp[t];
        const float mean = stats[t] * invE;
        const float var  = stats[16 + t] * invE - mean * mean;
        const float a    = gE[t] / sqrtf(var + 1e-5f);
        sA[t] = a;
        sB[t] = bE[t] - mean * a;
    }
    __syncthreads();

    const int n = blockIdx.x * WG + t;
    float x[16];
#pragma unroll
    for (int k = 0; k < 16; ++k) x[k] = 0.f;

    if (n < N) {
        const float d    = deg[n];
        const float invd = 1.0f / fmaxf(d, 1.0f);
        float y[16];
#pragma unroll
        for (int k = 0; k < 16; ++k)
            y[k] = (sA[k] * S[16*(size_t)n + k] + sB[k] * d) * invd;
#pragma unroll
        for (int k = 0; k < 16; ++k) x[k] = sBp[k];
#pragma unroll
        for (int j = 0; j < 16; ++j) {
            const float yj = y[j];
#pragma unroll
            for (int k = 0; k < 16; ++k) x[k] += yj * sWp[j*16 + k];
        }
#pragma unroll
        for (int k = 0; k < 16; ++k) X[16*(size_t)n + k] = x[k];
    }

    float vs[16], vq[16];
#pragma unroll
    for (int k = 0; k < 16; ++k) { vs[k] = x[k]; vq[k] = x[k]*x[k]; }
#pragma unroll
    for (int k = 0; k < 16; ++k) {
        float a = vs[k], b = vq[k];
#pragma unroll
        for (int off = 32; off > 0; off >>= 1) {
            a += __shfl_down(a, off);
            b += __shfl_down(b, off);
        }
        vs[k] = a; vq[k] = b;
    }
    const int wave = t >> 6;
    if ((t & 63) == 0) {
#pragma unroll
        for (int k = 0; k < 16; ++k) {
            red[wave][k]      = vs[k];
            red[wave][16 + k] = vq[k];
        }
    }
    __syncthreads();
    if (t < 32) {
        const float s = red[0][t] + red[1][t] + red[2][t] + red[3][t];
        atomicAdd(&stats[32 + t], s);
    }
}

// -------------------- Kernel 3: apply node BN --------------------
__global__ __launch_bounds__(WG) void out_kernel(
    const float* __restrict__ X, const float* __restrict__ stats,
    const float* __restrict__ gN, const float* __restrict__ bN,
    float* __restrict__ out, int total, float invN)
{
    __shared__ float sA[16], sB[16];
    if (threadIdx.x < 16) {
        const int k = threadIdx.x;
        const float mean = stats[32 + k] * invN;
        const float var  = stats[48 + k] * invN - mean * mean;
        const float a    = gN[k] / sqrtf(var + 1e-5f);
        sA[k] = a;
        sB[k] = bN[k] - mean * a;
    }
    __syncthreads();
    const int i = blockIdx.x * WG + threadIdx.x;
    if (i < total) {
        out[i] = sA[i & 15] * X[i] + sB[i & 15];
    }
}

extern "C" void kernel_launch(void* const* d_in, const int* in_sizes, int n_in,
                              void* d_out, int out_size, void* d_ws, size_t ws_size,
                              hipStream_t stream)
{
    const float* coords  = (const float*)d_in[0];
    const float* normals = (const float*)d_in[1];
    const float* curv    = (const float*)d_in[2];
    const int*   eidx    = (const int*)d_in[3];
    const float* W1 = (const float*)d_in[4];
    const float* b1 = (const float*)d_in[5];
    const float* W2 = (const float*)d_in[6];
    const float* b2 = (const float*)d_in[7];
    const float* W3 = (const float*)d_in[8];
    const float* b3 = (const float*)d_in[9];
    const float* gE = (const float*)d_in[10];
    const float* bE = (const float*)d_in[11];
    const float* Wp = (const float*)d_in[12];
    const float* bp = (const float*)d_in[13];
    const float* gN = (const float*)d_in[14];
    const float* bN = (const float*)d_in[15];

    const int N = in_sizes[0] / 3;
    const int E = in_sizes[3] / 2;

    // workspace layout: S[N*16] | deg[N] | stats[64] | X[N*16]  (~13.3 MB)
    float* S     = (float*)d_ws;
    float* deg   = S + (size_t)N * 16;
    float* stats = deg + N;
    float* X     = stats + 64;

    const size_t zero_bytes = ((size_t)N * 16 + N + 64) * sizeof(float);
    hipMemsetAsync(d_ws, 0, zero_bytes, stream);

    const int egrid = 2048;
    edge_kernel<<<dim3(egrid), dim3(WG), 0, stream>>>(
        coords, normals, curv, eidx, W1, b1, W2, b2, W3, b3,
        S, deg, stats, E);

    node_kernel<<<dim3((N + WG - 1) / WG), dim3(WG), 0, stream>>>(
        S, deg, Wp, bp, gE, bE, X, stats, N, 1.0f / (float)E);

    out_kernel<<<dim3((N * 16 + WG - 1) / WG), dim3(WG), 0, stream>>>(
        X, stats, gN, bN, (float*)d_out, N * 16, 1.0f / (float)N);
}

// Round 2
// 1450.983 us; speedup vs baseline: 2.0757x; 2.0757x over previous
//
#include <hip/hip_runtime.h>
#include <hip/hip_fp16.h>
#include <math.h>

#define WG 256

__device__ __forceinline__ float gelu_f(float x) {
    return 0.5f * x * (1.0f + erff(x * 0.7071067811865476f));
}

// ============================ CSR PATH ============================

// ---- K1: per-edge MLP -> ef16[E,16], degree counts, edge-BN stats ----
__global__ __launch_bounds__(WG) void edge_mlp_kernel(
    const float* __restrict__ coords,
    const float* __restrict__ normals,
    const float* __restrict__ curv,
    const int*   __restrict__ eidx,
    const float* __restrict__ W1, const float* __restrict__ b1,
    const float* __restrict__ W2, const float* __restrict__ b2,
    const float* __restrict__ W3, const float* __restrict__ b3,
    __half* __restrict__ ef16, int* __restrict__ cnt,
    float* __restrict__ stats, int E)
{
    __shared__ float sW1[512];
    __shared__ float sW2[2048];
    __shared__ float sW3[512];
    __shared__ float sB1[64];
    __shared__ float sB2[32];
    __shared__ float sB3[16];
    __shared__ float red[4][32];

    const int t = threadIdx.x;
    for (int i = t; i < 512;  i += WG) sW1[i] = W1[i];
    for (int i = t; i < 2048; i += WG) sW2[i] = W2[i];
    for (int i = t; i < 512;  i += WG) sW3[i] = W3[i];
    if (t < 64) sB1[t] = b1[t];
    if (t < 32) sB2[t] = b2[t];
    if (t < 16) sB3[t] = b3[t];
    __syncthreads();

    float vsum[16], vsq[16];
#pragma unroll
    for (int k = 0; k < 16; ++k) { vsum[k] = 0.f; vsq[k] = 0.f; }

    const int e = blockIdx.x * WG + t;
    if (e < E) {
        const int r = eidx[e];
        const int c = eidx[E + e];

        const float rx = coords[3*r], ry = coords[3*r+1], rz = coords[3*r+2];
        const float cx = coords[3*c], cy = coords[3*c+1], cz = coords[3*c+2];
        const float dx = cx - rx, dy = cy - ry, dz = cz - rz;
        const float nrx = normals[3*r], nry = normals[3*r+1], nrz = normals[3*r+2];
        const float ncx = normals[3*c], ncy = normals[3*c+1], ncz = normals[3*c+2];

        const float ndot = nrx*ncx + nry*ncy + nrz*ncz;
        const float dn   = sqrtf(dx*dx + dy*dy + dz*dz) + 1e-8f;
        const float inv  = 1.0f / dn;
        const float lo = -1.0f + 1e-8f, hi = 1.0f - 1e-8f;
        const float cr = fminf(fmaxf((nrx*dx + nry*dy + nrz*dz) * inv, lo), hi);
        const float cc = fminf(fmaxf((ncx*dx + ncy*dy + ncz*dz) * inv, lo), hi);
        const float cd0 = curv[4*c]   - curv[4*r];
        const float cd1 = curv[4*c+1] - curv[4*r+1];

        const float f[8] = {dx, dy, dz, ndot, cr, cc, cd0, cd1};

        float acc2[32];
#pragma unroll
        for (int j = 0; j < 32; ++j) acc2[j] = sB2[j];
        for (int i = 0; i < 64; ++i) {
            float a = sB1[i];
#pragma unroll
            for (int k = 0; k < 8; ++k) a += f[k] * sW1[k*64 + i];
            const float g = gelu_f(a);
#pragma unroll
            for (int j = 0; j < 32; ++j) acc2[j] += g * sW2[i*32 + j];
        }
        float ef[16];
#pragma unroll
        for (int k = 0; k < 16; ++k) ef[k] = sB3[k];
#pragma unroll
        for (int i = 0; i < 32; ++i) {
            const float g = gelu_f(acc2[i]);
#pragma unroll
            for (int k = 0; k < 16; ++k) ef[k] += g * sW3[i*16 + k];
        }

        // store as f16 [E,16] — 32B per edge, 16B-aligned vector stores
        __half2 hv[8];
#pragma unroll
        for (int k2 = 0; k2 < 8; ++k2) hv[k2] = __floats2half2_rn(ef[2*k2], ef[2*k2+1]);
        float4* dst = (float4*)(ef16 + (size_t)e * 16);
        dst[0] = *(float4*)&hv[0];
        dst[1] = *(float4*)&hv[4];

        atomicAdd(&cnt[r], 1);
        atomicAdd(&cnt[c], 1);

#pragma unroll
        for (int k = 0; k < 16; ++k) { vsum[k] = ef[k]; vsq[k] = ef[k]*ef[k]; }
    }

    // block reduction of edge-BN stats
#pragma unroll
    for (int k = 0; k < 16; ++k) {
        float a = vsum[k], b = vsq[k];
#pragma unroll
        for (int off = 32; off > 0; off >>= 1) {
            a += __shfl_down(a, off);
            b += __shfl_down(b, off);
        }
        vsum[k] = a; vsq[k] = b;
    }
    const int wave = t >> 6;
    if ((t & 63) == 0) {
#pragma unroll
        for (int k = 0; k < 16; ++k) {
            red[wave][k]      = vsum[k];
            red[wave][16 + k] = vsq[k];
        }
    }
    __syncthreads();
    if (t < 32) {
        const float s = red[0][t] + red[1][t] + red[2][t] + red[3][t];
        atomicAdd(&stats[t], s);
    }
}

// ---- scan: cnt -> exclusive prefix (rowptr), plus cursor copy ----
__global__ __launch_bounds__(WG) void scan_blocks_kernel(
    const int* __restrict__ cnt, int* __restrict__ rowptr,
    int* __restrict__ bsum, int N)
{
    __shared__ int sd[WG];
    const int t = threadIdx.x;
    const int i = blockIdx.x * WG + t;
    const int v = (i < N) ? cnt[i] : 0;
    sd[t] = v;
    __syncthreads();
    for (int off = 1; off < WG; off <<= 1) {
        int x = 0;
        if (t >= off) x = sd[t - off];
        __syncthreads();
        sd[t] += x;
        __syncthreads();
    }
    if (i < N) rowptr[i] = sd[t] - v;      // exclusive
    if (t == WG - 1) bsum[blockIdx.x] = sd[t];
}

__global__ __launch_bounds__(512) void scan_top_kernel(
    const int* __restrict__ bsum, int* __restrict__ boff, int nblk)
{
    __shared__ int sd[512];
    const int t = threadIdx.x;
    const int v = (t < nblk) ? bsum[t] : 0;
    sd[t] = v;
    __syncthreads();
    for (int off = 1; off < 512; off <<= 1) {
        int x = 0;
        if (t >= off) x = sd[t - off];
        __syncthreads();
        sd[t] += x;
        __syncthreads();
    }
    if (t < nblk) boff[t] = sd[t] - v;     // exclusive
}

__global__ __launch_bounds__(WG) void scan_add_kernel(
    int* __restrict__ rowptr, int* __restrict__ cursor,
    const int* __restrict__ boff, int N)
{
    const int i = blockIdx.x * WG + threadIdx.x;
    if (i < N) {
        const int v = rowptr[i] + boff[blockIdx.x];
        rowptr[i] = v;
        cursor[i] = v;
    }
}

// ---- build CSR incidence slots ----
__global__ __launch_bounds__(WG) void build_kernel(
    const int* __restrict__ eidx, int* __restrict__ cursor,
    int* __restrict__ slots, int E)
{
    const int e = blockIdx.x * WG + threadIdx.x;
    if (e < E) {
        const int r = eidx[e];
        const int c = eidx[E + e];
        const int p = atomicAdd(&cursor[r], 1);
        slots[p] = e;
        const int q = atomicAdd(&cursor[c], 1);
        slots[q] = e;
    }
}

// ---- gather + edge-BN affine + degree norm + projection + node-BN stats ----
__global__ __launch_bounds__(WG) void gather_kernel(
    const __half* __restrict__ ef16, const int* __restrict__ slots,
    const int* __restrict__ rowptr, const int* __restrict__ cnt,
    const float* __restrict__ Wp, const float* __restrict__ bp,
    const float* __restrict__ gE, const float* __restrict__ bE,
    float* __restrict__ stats, float* __restrict__ X,
    int N, float invE)
{
    __shared__ float sWp[256];
    __shared__ float sBp[16];
    __shared__ float sy[256];
    __shared__ float red[4][32];

    const int t = threadIdx.x;
    sWp[t] = Wp[t];
    if (t < 16) sBp[t] = bp[t];

    const int k = t & 15;
    const float mean = stats[k] * invE;
    const float var  = stats[16 + k] * invE - mean * mean;
    const float a_k  = gE[k] * rsqrtf(var + 1e-5f);
    const float b_k  = bE[k] - mean * a_k;

    const int wave = t >> 6;
    const int lane = t & 63;
    const int node = blockIdx.x * 16 + wave * 4 + (lane >> 4);

    float s = 0.f;
    int len = 0;
    if (node < N) {
        len = cnt[node];
        const int* sl = slots + rowptr[node];
        int i = 0;
        for (; i + 4 <= len; i += 4) {
            const int e0 = sl[i], e1 = sl[i+1], e2 = sl[i+2], e3 = sl[i+3];
            s += __half2float(ef16[(size_t)e0*16 + k])
               + __half2float(ef16[(size_t)e1*16 + k])
               + __half2float(ef16[(size_t)e2*16 + k])
               + __half2float(ef16[(size_t)e3*16 + k]);
        }
        for (; i < len; ++i) {
            const int e0 = sl[i];
            s += __half2float(ef16[(size_t)e0*16 + k]);
        }
    }
    const float d = (float)len;
    const float y = (a_k * s + b_k * d) / fmaxf(d, 1.0f);

    __syncthreads();          // sWp/sBp ready; also before sy write reuse
    sy[t] = y;
    __syncthreads();

    float x = sBp[k];
    const int base = t & ~15;
#pragma unroll
    for (int j = 0; j < 16; ++j) x += sy[base + j] * sWp[j*16 + k];

    if (node < N) X[(size_t)node*16 + k] = x;
    const float xs = (node < N) ? x : 0.f;

    // node-BN stats: reduce across the 4 groups of each wave, then waves
    float vs = xs, vq = xs * xs;
    vs += __shfl_xor(vs, 16); vq += __shfl_xor(vq, 16);
    vs += __shfl_xor(vs, 32); vq += __shfl_xor(vq, 32);
    if (lane < 16) {
        red[wave][k]      = vs;
        red[wave][16 + k] = vq;
    }
    __syncthreads();
    if (t < 32) {
        const float ssum = red[0][t] + red[1][t] + red[2][t] + red[3][t];
        atomicAdd(&stats[32 + t], ssum);
    }
}

// ---- apply node BN ----
__global__ __launch_bounds__(WG) void out_kernel(
    const float* __restrict__ X, const float* __restrict__ stats,
    const float* __restrict__ gN, const float* __restrict__ bN,
    float* __restrict__ out, int total, float invN)
{
    __shared__ float sA[16], sB[16];
    if (threadIdx.x < 16) {
        const int k = threadIdx.x;
        const float mean = stats[32 + k] * invN;
        const float var  = stats[48 + k] * invN - mean * mean;
        const float a    = gN[k] / sqrtf(var + 1e-5f);
        sA[k] = a;
        sB[k] = bN[k] - mean * a;
    }
    __syncthreads();
    const int i = blockIdx.x * WG + threadIdx.x;
    if (i < total) {
        out[i] = sA[i & 15] * X[i] + sB[i & 15];
    }
}

// ============================ FALLBACK (atomic) PATH ============================

__global__ __launch_bounds__(WG) void edge_kernel_fb(
    const float* __restrict__ coords,
    const float* __restrict__ normals,
    const float* __restrict__ curv,
    const int*   __restrict__ eidx,
    const float* __restrict__ W1, const float* __restrict__ b1,
    const float* __restrict__ W2, const float* __restrict__ b2,
    const float* __restrict__ W3, const float* __restrict__ b3,
    float* __restrict__ S, float* __restrict__ deg,
    float* __restrict__ stats, int E)
{
    __shared__ float sW1[512];
    __shared__ float sW2[2048];
    __shared__ float sW3[512];
    __shared__ float sB1[64];
    __shared__ float sB2[32];
    __shared__ float sB3[16];
    __shared__ float red[4][32];

    const int t = threadIdx.x;
    for (int i = t; i < 512;  i += WG) sW1[i] = W1[i];
    for (int i = t; i < 2048; i += WG) sW2[i] = W2[i];
    for (int i = t; i < 512;  i += WG) sW3[i] = W3[i];
    if (t < 64) sB1[t] = b1[t];
    if (t < 32) sB2[t] = b2[t];
    if (t < 16) sB3[t] = b3[t];
    __syncthreads();

    float vsum[16], vsq[16];
#pragma unroll
    for (int k = 0; k < 16; ++k) { vsum[k] = 0.f; vsq[k] = 0.f; }

    const int stride = gridDim.x * WG;
    for (int e = blockIdx.x * WG + t; e < E; e += stride) {
        const int r = eidx[e];
        const int c = eidx[E + e];

        const float rx = coords[3*r], ry = coords[3*r+1], rz = coords[3*r+2];
        const float cx = coords[3*c], cy = coords[3*c+1], cz = coords[3*c+2];
        const float dx = cx - rx, dy = cy - ry, dz = cz - rz;
        const float nrx = normals[3*r], nry = normals[3*r+1], nrz = normals[3*r+2];
        const float ncx = normals[3*c], ncy = normals[3*c+1], ncz = normals[3*c+2];

        const float ndot = nrx*ncx + nry*ncy + nrz*ncz;
        const float dn   = sqrtf(dx*dx + dy*dy + dz*dz) + 1e-8f;
        const float inv  = 1.0f / dn;
        const float lo = -1.0f + 1e-8f, hi = 1.0f - 1e-8f;
        const float cr = fminf(fmaxf((nrx*dx + nry*dy + nrz*dz) * inv, lo), hi);
        const float cc = fminf(fmaxf((ncx*dx + ncy*dy + ncz*dz) * inv, lo), hi);
        const float cd0 = curv[4*c]   - curv[4*r];
        const float cd1 = curv[4*c+1] - curv[4*r+1];

        const float f[8] = {dx, dy, dz, ndot, cr, cc, cd0, cd1};

        float acc2[32];
#pragma unroll
        for (int j = 0; j < 32; ++j) acc2[j] = sB2[j];
        for (int i = 0; i < 64; ++i) {
            float a = sB1[i];
#pragma unroll
            for (int k = 0; k < 8; ++k) a += f[k] * sW1[k*64 + i];
            const float g = gelu_f(a);
#pragma unroll
            for (int j = 0; j < 32; ++j) acc2[j] += g * sW2[i*32 + j];
        }
        float ef[16];
#pragma unroll
        for (int k = 0; k < 16; ++k) ef[k] = sB3[k];
#pragma unroll
        for (int i = 0; i < 32; ++i) {
            const float g = gelu_f(acc2[i]);
#pragma unroll
            for (int k = 0; k < 16; ++k) ef[k] += g * sW3[i*16 + k];
        }

#pragma unroll
        for (int k = 0; k < 16; ++k) {
            atomicAdd(&S[16*(size_t)r + k], ef[k]);
            atomicAdd(&S[16*(size_t)c + k], ef[k]);
            vsum[k] += ef[k];
            vsq[k]  += ef[k] * ef[k];
        }
        atomicAdd(&deg[r], 1.0f);
        atomicAdd(&deg[c], 1.0f);
    }

#pragma unroll
    for (int k = 0; k < 16; ++k) {
        float a = vsum[k], b = vsq[k];
#pragma unroll
        for (int off = 32; off > 0; off >>= 1) {
            a += __shfl_down(a, off);
            b += __shfl_down(b, off);
        }
        vsum[k] = a; vsq[k] = b;
    }
    const int wave = t >> 6;
    if ((t & 63) == 0) {
#pragma unroll
        for (int k = 0; k < 16; ++k) {
            red[wave][k]      = vsum[k];
            red[wave][16 + k] = vsq[k];
        }
    }
    __syncthreads();
    if (t < 32) {
        const float s = red[0][t] + red[1][t] + red[2][t] + red[3][t];
        atomicAdd(&stats[t], s);
    }
}

__global__ __launch_bounds__(WG) void node_kernel_fb(
    const float* __restrict__ S, const float* __restrict__ deg,
    const float* __restrict__ Wp, const float* __restrict__ bp,
    const float* __restrict__ gE, const float* __restrict__ bE,
    float* __restrict__ X, float* __restrict__ stats,
    int N, float invE)
{
    __shared__ float sWp[256];
    __shared__ float sBp[16];
    __shared__ float sA[16], sB[16];
    __shared__ float red[4][32];

    const int t = threadIdx.x;
    sWp[t] = Wp[t & 255];
    if (t < 16) {
        sBp[t] = bp[t];
        const float mean = stats[t] * invE;
        const float var  = stats[16 + t] * invE - mean * mean;
        const float a    = gE[t] / sqrtf(var + 1e-5f);
        sA[t] = a;
        sB[t] = bE[t] - mean * a;
    }
    __syncthreads();

    const int n = blockIdx.x * WG + t;
    float x[16];
#pragma unroll
    for (int k = 0; k < 16; ++k) x[k] = 0.f;

    if (n < N) {
        const float d    = deg[n];
        const float invd = 1.0f / fmaxf(d, 1.0f);
        float y[16];
#pragma unroll
        for (int k = 0; k < 16; ++k)
            y[k] = (sA[k] * S[16*(size_t)n + k] + sB[k] * d) * invd;
#pragma unroll
        for (int k = 0; k < 16; ++k) x[k] = sBp[k];
#pragma unroll
        for (int j = 0; j < 16; ++j) {
            const float yj = y[j];
#pragma unroll
            for (int k = 0; k < 16; ++k) x[k] += yj * sWp[j*16 + k];
        }
#pragma unroll
        for (int k = 0; k < 16; ++k) X[16*(size_t)n + k] = x[k];
    }

    float vs[16], vq[16];
#pragma unroll
    for (int k = 0; k < 16; ++k) { vs[k] = x[k]; vq[k] = x[k]*x[k]; }
#pragma unroll
    for (int k = 0; k < 16; ++k) {
        float a = vs[k], b = vq[k];
#pragma unroll
        for (int off = 32; off > 0; off >>= 1) {
            a += __shfl_down(a, off);
            b += __shfl_down(b, off);
        }
        vs[k] = a; vq[k] = b;
    }
    const int wave = t >> 6;
    if ((t & 63) == 0) {
#pragma unroll
        for (int k = 0; k < 16; ++k) {
            red[wave][k]      = vs[k];
            red[wave][16 + k] = vq[k];
        }
    }
    __syncthreads();
    if (t < 32) {
        const float s = red[0][t] + red[1][t] + red[2][t] + red[3][t];
        atomicAdd(&stats[32 + t], s);
    }
}

// ============================ LAUNCH ============================

extern "C" void kernel_launch(void* const* d_in, const int* in_sizes, int n_in,
                              void* d_out, int out_size, void* d_ws, size_t ws_size,
                              hipStream_t stream)
{
    const float* coords  = (const float*)d_in[0];
    const float* normals = (const float*)d_in[1];
    const float* curv    = (const float*)d_in[2];
    const int*   eidx    = (const int*)d_in[3];
    const float* W1 = (const float*)d_in[4];
    const float* b1 = (const float*)d_in[5];
    const float* W2 = (const float*)d_in[6];
    const float* b2 = (const float*)d_in[7];
    const float* W3 = (const float*)d_in[8];
    const float* b3 = (const float*)d_in[9];
    const float* gE = (const float*)d_in[10];
    const float* bE = (const float*)d_in[11];
    const float* Wp = (const float*)d_in[12];
    const float* bp = (const float*)d_in[13];
    const float* gN = (const float*)d_in[14];
    const float* bN = (const float*)d_in[15];

    const int N = in_sizes[0] / 3;
    const int E = in_sizes[3] / 2;
    const int nblk = (N + WG - 1) / WG;

    // CSR-path layout:
    // stats[64] | cnt[N] | rowptr[N] | cursor[N] | bsum[4096] | boff[4096]
    // | slots[2E] | X[N*16 f32] | ef16[E*16 f16]
    const size_t need = (size_t)(64 + 3*(size_t)N + 8192 + 2*(size_t)E) * 4
                      + (size_t)N * 64 + (size_t)E * 32 + 256;

    if (ws_size >= need && nblk <= 4096) {
        float* stats  = (float*)d_ws;
        int*   cnt    = (int*)(stats + 64);
        int*   rowptr = cnt + N;
        int*   cursor = rowptr + N;
        int*   bsum   = cursor + N;
        int*   boff   = bsum + 4096;
        int*   slots  = boff + 4096;
        float* X      = (float*)(slots + 2*(size_t)E);
        __half* ef16  = (__half*)(X + (size_t)N * 16);

        hipMemsetAsync(d_ws, 0, (size_t)(64 + N) * 4, stream);

        const int eblk = (E + WG - 1) / WG;
        edge_mlp_kernel<<<dim3(eblk), dim3(WG), 0, stream>>>(
            coords, normals, curv, eidx, W1, b1, W2, b2, W3, b3,
            ef16, cnt, stats, E);

        scan_blocks_kernel<<<dim3(nblk), dim3(WG), 0, stream>>>(cnt, rowptr, bsum, N);
        scan_top_kernel<<<dim3(1), dim3(512), 0, stream>>>(bsum, boff, nblk);
        scan_add_kernel<<<dim3(nblk), dim3(WG), 0, stream>>>(rowptr, cursor, boff, N);

        build_kernel<<<dim3(eblk), dim3(WG), 0, stream>>>(eidx, cursor, slots, E);

        gather_kernel<<<dim3((N + 15) / 16), dim3(WG), 0, stream>>>(
            ef16, slots, rowptr, cnt, Wp, bp, gE, bE, stats, X, N, 1.0f / (float)E);

        out_kernel<<<dim3((N * 16 + WG - 1) / WG), dim3(WG), 0, stream>>>(
            X, stats, gN, bN, (float*)d_out, N * 16, 1.0f / (float)N);
    } else {
        // fallback: round-1 atomic path
        float* S     = (float*)d_ws;
        float* deg   = S + (size_t)N * 16;
        float* stats = deg + N;
        float* X     = stats + 64;

        hipMemsetAsync(d_ws, 0, ((size_t)N * 16 + N + 64) * sizeof(float), stream);

        edge_kernel_fb<<<dim3(2048), dim3(WG), 0, stream>>>(
            coords, normals, curv, eidx, W1, b1, W2, b2, W3, b3,
            S, deg, stats, E);

        node_kernel_fb<<<dim3((N + WG - 1) / WG), dim3(WG), 0, stream>>>(
            S, deg, Wp, bp, gE, bE, X, stats, N, 1.0f / (float)E);

        out_kernel<<<dim3((N * 16 + WG - 1) / WG), dim3(WG), 0, stream>>>(
            X, stats, gN, bN, (float*)d_out, N * 16, 1.0f / (float)N);
    }
}

// Round 3
// 694.273 us; speedup vs baseline: 4.3380x; 2.0899x over previous
//
#include <hip/hip_runtime.h>
#include <hip/hip_fp16.h>
#include <math.h>

#define WG 256

typedef _Float16 f16x8 __attribute__((ext_vector_type(8)));
typedef float    f32x4 __attribute__((ext_vector_type(4)));

__device__ __forceinline__ float gelu_f(float x) {
    return 0.5f * x * (1.0f + erff(x * 0.7071067811865476f));
}

// wave-private LDS fence: drain DS queue + compiler memory barrier
#define WAVE_LDS_FENCE() asm volatile("s_waitcnt lgkmcnt(0)" ::: "memory")

// ============================ CSR PATH ============================

// ---- K1: per-edge MLP via MFMA -> ef16[E,16], degree counts, edge-BN stats ----
// Per wave: 64 edges. F[64,8]@W1[8,64] -> gelu -> @W2[64,32] -> gelu -> @W3[32,16].
// mfma_f32_16x16x32_f16: A[m=lane&15][k=quad*8+j], B[k=quad*8+j][n=lane&15],
// C/D: col=lane&15, row=quad*4+reg  (learn_hip m89-verified layout family).
__global__ __launch_bounds__(WG, 4) void edge_mlp_mfma(
    const float* __restrict__ coords,
    const float* __restrict__ normals,
    const float* __restrict__ curv,
    const int*   __restrict__ eidx,
    const float* __restrict__ W1, const float* __restrict__ b1,
    const float* __restrict__ W2, const float* __restrict__ b2,
    const float* __restrict__ W3, const float* __restrict__ b3,
    __half* __restrict__ ef16, int* __restrict__ cnt,
    float* __restrict__ stats, int E)
{
    // per-wave staging, padded rows (72/40 halfs) to spread banks; rows 16B-aligned
    __shared__ _Float16 h1s[4][16][72];
    __shared__ _Float16 h2s[4][16][40];
    __shared__ float red[4][32];

    const int t    = threadIdx.x;
    const int w    = t >> 6;
    const int lane = t & 63;
    const int quad = lane >> 4;
    const int col  = lane & 15;

    // ---- weight B-fragments in registers (once per thread) ----
    f16x8 bw1[4];
#pragma unroll
    for (int n = 0; n < 4; ++n) {
#pragma unroll
        for (int j = 0; j < 8; ++j) {
            const int k = quad * 8 + j;
            bw1[n][j] = (k < 8) ? (_Float16)W1[k * 64 + n * 16 + col] : (_Float16)0.f;
        }
    }
    f16x8 bw2[2][2];
#pragma unroll
    for (int s = 0; s < 2; ++s)
#pragma unroll
        for (int n = 0; n < 2; ++n)
#pragma unroll
            for (int j = 0; j < 8; ++j)
                bw2[s][n][j] = (_Float16)W2[(s * 32 + quad * 8 + j) * 32 + n * 16 + col];
    f16x8 bw3;
#pragma unroll
    for (int j = 0; j < 8; ++j)
        bw3[j] = (_Float16)W3[(quad * 8 + j) * 16 + col];

    float b1v[4], b2v[2], b3v;
#pragma unroll
    for (int n = 0; n < 4; ++n) b1v[n] = b1[n * 16 + col];
    b2v[0] = b2[col]; b2v[1] = b2[16 + col];
    b3v = b3[col];

    // ---- per-lane edge geometry -> f[8] ----
    const int e  = blockIdx.x * WG + w * 64 + lane;
    const bool ev = (e < E);
    const int ec = ev ? e : 0;
    const int r = eidx[ec];
    const int c = eidx[E + ec];

    const float rx = coords[3*r], ry = coords[3*r+1], rz = coords[3*r+2];
    const float cx = coords[3*c], cy = coords[3*c+1], cz = coords[3*c+2];
    const float dx = cx - rx, dy = cy - ry, dz = cz - rz;
    const float nrx = normals[3*r], nry = normals[3*r+1], nrz = normals[3*r+2];
    const float ncx = normals[3*c], ncy = normals[3*c+1], ncz = normals[3*c+2];

    const float ndot = nrx*ncx + nry*ncy + nrz*ncz;
    const float dn   = sqrtf(dx*dx + dy*dy + dz*dz) + 1e-8f;
    const float inv  = 1.0f / dn;
    const float lo = -1.0f + 1e-8f, hi = 1.0f - 1e-8f;
    const float cr = fminf(fmaxf((nrx*dx + nry*dy + nrz*dz) * inv, lo), hi);
    const float cc = fminf(fmaxf((ncx*dx + ncy*dy + ncz*dz) * inv, lo), hi);
    const float cd0 = curv[4*c]   - curv[4*r];
    const float cd1 = curv[4*c+1] - curv[4*r+1];

    float f[8] = {dx, dy, dz, ndot, cr, cc, cd0, cd1};

    if (ev) {
        atomicAdd(&cnt[r], 1);
        atomicAdd(&cnt[c], 1);
    }

    const int e0w = blockIdx.x * WG + w * 64;   // wave's base edge

    float vsum = 0.f, vsq = 0.f;                // edge-BN stats for col

    // ---- 4 m-tiles of 16 edges ----
#pragma unroll
    for (int mt = 0; mt < 4; ++mt) {
        // A1: features of edges mt*16..mt*16+15 into quad-0 lanes
        f16x8 a1;
#pragma unroll
        for (int j = 0; j < 8; ++j) {
            const float v = __shfl(f[j], (mt << 4) + col, 64);
            a1[j] = (quad == 0) ? (_Float16)v : (_Float16)0.f;
        }

        // layer 1: 4 n-tiles, bias in C-init
        f32x4 c1[4];
#pragma unroll
        for (int n = 0; n < 4; ++n) {
            f32x4 c0 = {b1v[n], b1v[n], b1v[n], b1v[n]};
            c1[n] = __builtin_amdgcn_mfma_f32_16x16x32_f16(a1, bw1[n], c0, 0, 0, 0);
        }
        // gelu -> h1 staging [edge][feat]
#pragma unroll
        for (int n = 0; n < 4; ++n)
#pragma unroll
            for (int rg = 0; rg < 4; ++rg)
                h1s[w][quad * 4 + rg][n * 16 + col] = (_Float16)gelu_f(c1[n][rg]);

        WAVE_LDS_FENCE();

        // layer 2: A from staging (b128), K=64 in 2 steps, 2 n-tiles
        const f16x8 a2s0 = *(const f16x8*)&h1s[w][col][quad * 8];
        const f16x8 a2s1 = *(const f16x8*)&h1s[w][col][32 + quad * 8];
        f32x4 c2[2];
#pragma unroll
        for (int n = 0; n < 2; ++n) {
            f32x4 c0 = {b2v[n], b2v[n], b2v[n], b2v[n]};
            c0 = __builtin_amdgcn_mfma_f32_16x16x32_f16(a2s0, bw2[0][n], c0, 0, 0, 0);
            c2[n] = __builtin_amdgcn_mfma_f32_16x16x32_f16(a2s1, bw2[1][n], c0, 0, 0, 0);
        }
        // gelu -> h2 staging
#pragma unroll
        for (int n = 0; n < 2; ++n)
#pragma unroll
            for (int rg = 0; rg < 4; ++rg)
                h2s[w][quad * 4 + rg][n * 16 + col] = (_Float16)gelu_f(c2[n][rg]);

        WAVE_LDS_FENCE();

        // layer 3
        const f16x8 a3 = *(const f16x8*)&h2s[w][col][quad * 8];
        f32x4 c0 = {b3v, b3v, b3v, b3v};
        const f32x4 c3 = __builtin_amdgcn_mfma_f32_16x16x32_f16(a3, bw3, c0, 0, 0, 0);

        // store ef16 + accumulate edge-BN stats (col is fixed per lane)
#pragma unroll
        for (int rg = 0; rg < 4; ++rg) {
            const int me = e0w + mt * 16 + quad * 4 + rg;
            if (me < E) {
                const float v = c3[rg];
                ef16[(size_t)me * 16 + col] = __float2half(v);
                vsum += v;
                vsq  += v * v;
            }
        }
    }

    // reduce stats across quads (lanes with same col)
    vsum += __shfl_xor(vsum, 16, 64);
    vsq  += __shfl_xor(vsq,  16, 64);
    vsum += __shfl_xor(vsum, 32, 64);
    vsq  += __shfl_xor(vsq,  32, 64);
    if (lane < 16) {
        red[w][col]      = vsum;
        red[w][16 + col] = vsq;
    }
    __syncthreads();
    if (t < 32) {
        const float s = red[0][t] + red[1][t] + red[2][t] + red[3][t];
        atomicAdd(&stats[t], s);
    }
}

// ---- scan: cnt -> exclusive prefix (rowptr), plus cursor copy ----
__global__ __launch_bounds__(WG) void scan_blocks_kernel(
    const int* __restrict__ cnt, int* __restrict__ rowptr,
    int* __restrict__ bsum, int N)
{
    __shared__ int sd[WG];
    const int t = threadIdx.x;
    const int i = blockIdx.x * WG + t;
    const int v = (i < N) ? cnt[i] : 0;
    sd[t] = v;
    __syncthreads();
    for (int off = 1; off < WG; off <<= 1) {
        int x = 0;
        if (t >= off) x = sd[t - off];
        __syncthreads();
        sd[t] += x;
        __syncthreads();
    }
    if (i < N) rowptr[i] = sd[t] - v;      // exclusive
    if (t == WG - 1) bsum[blockIdx.x] = sd[t];
}

__global__ __launch_bounds__(512) void scan_top_kernel(
    const int* __restrict__ bsum, int* __restrict__ boff, int nblk)
{
    __shared__ int sd[512];
    const int t = threadIdx.x;
    const int v = (t < nblk) ? bsum[t] : 0;
    sd[t] = v;
    __syncthreads();
    for (int off = 1; off < 512; off <<= 1) {
        int x = 0;
        if (t >= off) x = sd[t - off];
        __syncthreads();
        sd[t] += x;
        __syncthreads();
    }
    if (t < nblk) boff[t] = sd[t] - v;     // exclusive
}

__global__ __launch_bounds__(WG) void scan_add_kernel(
    int* __restrict__ rowptr, int* __restrict__ cursor,
    const int* __restrict__ boff, int N)
{
    const int i = blockIdx.x * WG + threadIdx.x;
    if (i < N) {
        const int v = rowptr[i] + boff[blockIdx.x];
        rowptr[i] = v;
        cursor[i] = v;
    }
}

// ---- build CSR incidence slots ----
__global__ __launch_bounds__(WG) void build_kernel(
    const int* __restrict__ eidx, int* __restrict__ cursor,
    int* __restrict__ slots, int E)
{
    const int e = blockIdx.x * WG + threadIdx.x;
    if (e < E) {
        const int r = eidx[e];
        const int c = eidx[E + e];
        const int p = atomicAdd(&cursor[r], 1);
        slots[p] = e;
        const int q = atomicAdd(&cursor[c], 1);
        slots[q] = e;
    }
}

// ---- gather + edge-BN affine + degree norm + projection + node-BN stats ----
__global__ __launch_bounds__(WG) void gather_kernel(
    const __half* __restrict__ ef16, const int* __restrict__ slots,
    const int* __restrict__ rowptr, const int* __restrict__ cnt,
    const float* __restrict__ Wp, const float* __restrict__ bp,
    const float* __restrict__ gE, const float* __restrict__ bE,
    float* __restrict__ stats, float* __restrict__ X,
    int N, float invE)
{
    __shared__ float sWp[256];
    __shared__ float sBp[16];
    __shared__ float sy[256];
    __shared__ float red[4][32];

    const int t = threadIdx.x;
    sWp[t] = Wp[t];
    if (t < 16) sBp[t] = bp[t];

    const int k = t & 15;
    const float mean = stats[k] * invE;
    const float var  = stats[16 + k] * invE - mean * mean;
    const float a_k  = gE[k] * rsqrtf(var + 1e-5f);
    const float b_k  = bE[k] - mean * a_k;

    const int wave = t >> 6;
    const int lane = t & 63;
    const int node = blockIdx.x * 16 + wave * 4 + (lane >> 4);

    float s = 0.f;
    int len = 0;
    if (node < N) {
        len = cnt[node];
        const int* sl = slots + rowptr[node];
        int i = 0;
        for (; i + 4 <= len; i += 4) {
            const int e0 = sl[i], e1 = sl[i+1], e2 = sl[i+2], e3 = sl[i+3];
            s += __half2float(ef16[(size_t)e0*16 + k])
               + __half2float(ef16[(size_t)e1*16 + k])
               + __half2float(ef16[(size_t)e2*16 + k])
               + __half2float(ef16[(size_t)e3*16 + k]);
        }
        for (; i < len; ++i) {
            const int e0 = sl[i];
            s += __half2float(ef16[(size_t)e0*16 + k]);
        }
    }
    const float d = (float)len;
    const float y = (a_k * s + b_k * d) / fmaxf(d, 1.0f);

    __syncthreads();
    sy[t] = y;
    __syncthreads();

    float x = sBp[k];
    const int base = t & ~15;
#pragma unroll
    for (int j = 0; j < 16; ++j) x += sy[base + j] * sWp[j*16 + k];

    if (node < N) X[(size_t)node*16 + k] = x;
    const float xs = (node < N) ? x : 0.f;

    float vs = xs, vq = xs * xs;
    vs += __shfl_xor(vs, 16); vq += __shfl_xor(vq, 16);
    vs += __shfl_xor(vs, 32); vq += __shfl_xor(vq, 32);
    if (lane < 16) {
        red[wave][k]      = vs;
        red[wave][16 + k] = vq;
    }
    __syncthreads();
    if (t < 32) {
        const float ssum = red[0][t] + red[1][t] + red[2][t] + red[3][t];
        atomicAdd(&stats[32 + t], ssum);
    }
}

// ---- apply node BN ----
__global__ __launch_bounds__(WG) void out_kernel(
    const float* __restrict__ X, const float* __restrict__ stats,
    const float* __restrict__ gN, const float* __restrict__ bN,
    float* __restrict__ out, int total, float invN)
{
    __shared__ float sA[16], sB[16];
    if (threadIdx.x < 16) {
        const int k = threadIdx.x;
        const float mean = stats[32 + k] * invN;
        const float var  = stats[48 + k] * invN - mean * mean;
        const float a    = gN[k] / sqrtf(var + 1e-5f);
        sA[k] = a;
        sB[k] = bN[k] - mean * a;
    }
    __syncthreads();
    const int i = blockIdx.x * WG + threadIdx.x;
    if (i < total) {
        out[i] = sA[i & 15] * X[i] + sB[i & 15];
    }
}

// ============================ FALLBACK (atomic) PATH ============================

__global__ __launch_bounds__(WG) void edge_kernel_fb(
    const float* __restrict__ coords,
    const float* __restrict__ normals,
    const float* __restrict__ curv,
    const int*   __restrict__ eidx,
    const float* __restrict__ W1, const float* __restrict__ b1,
    const float* __restrict__ W2, const float* __restrict__ b2,
    const float* __restrict__ W3, const float* __restrict__ b3,
    float* __restrict__ S, float* __restrict__ deg,
    float* __restrict__ stats, int E)
{
    __shared__ float sW1[512];
    __shared__ float sW2[2048];
    __shared__ float sW3[512];
    __shared__ float sB1[64];
    __shared__ float sB2[32];
    __shared__ float sB3[16];
    __shared__ float red[4][32];

    const int t = threadIdx.x;
    for (int i = t; i < 512;  i += WG) sW1[i] = W1[i];
    for (int i = t; i < 2048; i += WG) sW2[i] = W2[i];
    for (int i = t; i < 512;  i += WG) sW3[i] = W3[i];
    if (t < 64) sB1[t] = b1[t];
    if (t < 32) sB2[t] = b2[t];
    if (t < 16) sB3[t] = b3[t];
    __syncthreads();

    float vsum[16], vsq[16];
#pragma unroll
    for (int k = 0; k < 16; ++k) { vsum[k] = 0.f; vsq[k] = 0.f; }

    const int stride = gridDim.x * WG;
    for (int e = blockIdx.x * WG + t; e < E; e += stride) {
        const int r = eidx[e];
        const int c = eidx[E + e];

        const float rx = coords[3*r], ry = coords[3*r+1], rz = coords[3*r+2];
        const float cx = coords[3*c], cy = coords[3*c+1], cz = coords[3*c+2];
        const float dx = cx - rx, dy = cy - ry, dz = cz - rz;
        const float nrx = normals[3*r], nry = normals[3*r+1], nrz = normals[3*r+2];
        const float ncx = normals[3*c], ncy = normals[3*c+1], ncz = normals[3*c+2];

        const float ndot = nrx*ncx + nry*ncy + nrz*ncz;
        const float dn   = sqrtf(dx*dx + dy*dy + dz*dz) + 1e-8f;
        const float inv  = 1.0f / dn;
        const float lo = -1.0f + 1e-8f, hi = 1.0f - 1e-8f;
        const float cr = fminf(fmaxf((nrx*dx + nry*dy + nrz*dz) * inv, lo), hi);
        const float cc = fminf(fmaxf((ncx*dx + ncy*dy + ncz*dz) * inv, lo), hi);
        const float cd0 = curv[4*c]   - curv[4*r];
        const float cd1 = curv[4*c+1] - curv[4*r+1];

        const float f[8] = {dx, dy, dz, ndot, cr, cc, cd0, cd1};

        float acc2[32];
#pragma unroll
        for (int j = 0; j < 32; ++j) acc2[j] = sB2[j];
        for (int i = 0; i < 64; ++i) {
            float a = sB1[i];
#pragma unroll
            for (int k = 0; k < 8; ++k) a += f[k] * sW1[k*64 + i];
            const float g = gelu_f(a);
#pragma unroll
            for (int j = 0; j < 32; ++j) acc2[j] += g * sW2[i*32 + j];
        }
        float ef[16];
#pragma unroll
        for (int k = 0; k < 16; ++k) ef[k] = sB3[k];
#pragma unroll
        for (int i = 0; i < 32; ++i) {
            const float g = gelu_f(acc2[i]);
#pragma unroll
            for (int k = 0; k < 16; ++k) ef[k] += g * sW3[i*16 + k];
        }

#pragma unroll
        for (int k = 0; k < 16; ++k) {
            atomicAdd(&S[16*(size_t)r + k], ef[k]);
            atomicAdd(&S[16*(size_t)c + k], ef[k]);
            vsum[k] += ef[k];
            vsq[k]  += ef[k] * ef[k];
        }
        atomicAdd(&deg[r], 1.0f);
        atomicAdd(&deg[c], 1.0f);
    }

#pragma unroll
    for (int k = 0; k < 16; ++k) {
        float a = vsum[k], b = vsq[k];
#pragma unroll
        for (int off = 32; off > 0; off >>= 1) {
            a += __shfl_down(a, off);
            b += __shfl_down(b, off);
        }
        vsum[k] = a; vsq[k] = b;
    }
    const int wave = t >> 6;
    if ((t & 63) == 0) {
#pragma unroll
        for (int k = 0; k < 16; ++k) {
            red[wave][k]      = vsum[k];
            red[wave][16 + k] = vsq[k];
        }
    }
    __syncthreads();
    if (t < 32) {
        const float s = red[0][t] + red[1][t] + red[2][t] + red[3][t];
        atomicAdd(&stats[t], s);
    }
}

__global__ __launch_bounds__(WG) void node_kernel_fb(
    const float* __restrict__ S, const float* __restrict__ deg,
    const float* __restrict__ Wp, const float* __restrict__ bp,
    const float* __restrict__ gE, const float* __restrict__ bE,
    float* __restrict__ X, float* __restrict__ stats,
    int N, float invE)
{
    __shared__ float sWp[256];
    __shared__ float sBp[16];
    __shared__ float sA[16], sB[16];
    __shared__ float red[4][32];

    const int t = threadIdx.x;
    sWp[t] = Wp[t & 255];
    if (t < 16) {
        sBp[t] = bp[t];
        const float mean = stats[t] * invE;
        const float var  = stats[16 + t] * invE - mean * mean;
        const float a    = gE[t] / sqrtf(var + 1e-5f);
        sA[t] = a;
        sB[t] = bE[t] - mean * a;
    }
    __syncthreads();

    const int n = blockIdx.x * WG + t;
    float x[16];
#pragma unroll
    for (int k = 0; k < 16; ++k) x[k] = 0.f;

    if (n < N) {
        const float d    = deg[n];
        const float invd = 1.0f / fmaxf(d, 1.0f);
        float y[16];
#pragma unroll
        for (int k = 0; k < 16; ++k)
            y[k] = (sA[k] * S[16*(size_t)n + k] + sB[k] * d) * invd;
#pragma unroll
        for (int k = 0; k < 16; ++k) x[k] = sBp[k];
#pragma unroll
        for (int j = 0; j < 16; ++j) {
            const float yj = y[j];
#pragma unroll
            for (int k = 0; k < 16; ++k) x[k] += yj * sWp[j*16 + k];
        }
#pragma unroll
        for (int k = 0; k < 16; ++k) X[16*(size_t)n + k] = x[k];
    }

    float vs[16], vq[16];
#pragma unroll
    for (int k = 0; k < 16; ++k) { vs[k] = x[k]; vq[k] = x[k]*x[k]; }
#pragma unroll
    for (int k = 0; k < 16; ++k) {
        float a = vs[k], b = vq[k];
#pragma unroll
        for (int off = 32; off > 0; off >>= 1) {
            a += __shfl_down(a, off);
            b += __shfl_down(b, off);
        }
        vs[k] = a; vq[k] = b;
    }
    const int wave = t >> 6;
    if ((t & 63) == 0) {
#pragma unroll
        for (int k = 0; k < 16; ++k) {
            red[wave][k]      = vs[k];
            red[wave][16 + k] = vq[k];
        }
    }
    __syncthreads();
    if (t < 32) {
        const float s = red[0][t] + red[1][t] + red[2][t] + red[3][t];
        atomicAdd(&stats[32 + t], s);
    }
}

// ============================ LAUNCH ============================

extern "C" void kernel_launch(void* const* d_in, const int* in_sizes, int n_in,
                              void* d_out, int out_size, void* d_ws, size_t ws_size,
                              hipStream_t stream)
{
    const float* coords  = (const float*)d_in[0];
    const float* normals = (const float*)d_in[1];
    const float* curv    = (const float*)d_in[2];
    const int*   eidx    = (const int*)d_in[3];
    const float* W1 = (const float*)d_in[4];
    const float* b1 = (const float*)d_in[5];
    const float* W2 = (const float*)d_in[6];
    const float* b2 = (const float*)d_in[7];
    const float* W3 = (const float*)d_in[8];
    const float* b3 = (const float*)d_in[9];
    const float* gE = (const float*)d_in[10];
    const float* bE = (const float*)d_in[11];
    const float* Wp = (const float*)d_in[12];
    const float* bp = (const float*)d_in[13];
    const float* gN = (const float*)d_in[14];
    const float* bN = (const float*)d_in[15];

    const int N = in_sizes[0] / 3;
    const int E = in_sizes[3] / 2;
    const int nblk = (N + WG - 1) / WG;

    // CSR-path layout:
    // stats[64] | cnt[N] | rowptr[N] | cursor[N] | bsum[4096] | boff[4096]
    // | slots[2E] | X[N*16 f32] | ef16[E*16 f16]
    const size_t need = (size_t)(64 + 3*(size_t)N + 8192 + 2*(size_t)E) * 4
                      + (size_t)N * 64 + (size_t)E * 32 + 256;

    if (ws_size >= need && nblk <= 4096) {
        float* stats  = (float*)d_ws;
        int*   cnt    = (int*)(stats + 64);
        int*   rowptr = cnt + N;
        int*   cursor = rowptr + N;
        int*   bsum   = cursor + N;
        int*   boff   = bsum + 4096;
        int*   slots  = boff + 4096;
        float* X      = (float*)(slots + 2*(size_t)E);
        __half* ef16  = (__half*)(X + (size_t)N * 16);

        hipMemsetAsync(d_ws, 0, (size_t)(64 + N) * 4, stream);

        const int eblk = (E + WG - 1) / WG;
        edge_mlp_mfma<<<dim3(eblk), dim3(WG), 0, stream>>>(
            coords, normals, curv, eidx, W1, b1, W2, b2, W3, b3,
            ef16, cnt, stats, E);

        scan_blocks_kernel<<<dim3(nblk), dim3(WG), 0, stream>>>(cnt, rowptr, bsum, N);
        scan_top_kernel<<<dim3(1), dim3(512), 0, stream>>>(bsum, boff, nblk);
        scan_add_kernel<<<dim3(nblk), dim3(WG), 0, stream>>>(rowptr, cursor, boff, N);

        build_kernel<<<dim3(eblk), dim3(WG), 0, stream>>>(eidx, cursor, slots, E);

        gather_kernel<<<dim3((N + 15) / 16), dim3(WG), 0, stream>>>(
            ef16, slots, rowptr, cnt, Wp, bp, gE, bE, stats, X, N, 1.0f / (float)E);

        out_kernel<<<dim3((N * 16 + WG - 1) / WG), dim3(WG), 0, stream>>>(
            X, stats, gN, bN, (float*)d_out, N * 16, 1.0f / (float)N);
    } else {
        // fallback: round-1 atomic path
        float* S     = (float*)d_ws;
        float* deg   = S + (size_t)N * 16;
        float* stats = deg + N;
        float* X     = stats + 64;

        hipMemsetAsync(d_ws, 0, ((size_t)N * 16 + N + 64) * sizeof(float), stream);

        edge_kernel_fb<<<dim3(2048), dim3(WG), 0, stream>>>(
            coords, normals, curv, eidx, W1, b1, W2, b2, W3, b3,
            S, deg, stats, E);

        node_kernel_fb<<<dim3((N + WG - 1) / WG), dim3(WG), 0, stream>>>(
            S, deg, Wp, bp, gE, bE, X, stats, N, 1.0f / (float)E);

        out_kernel<<<dim3((N * 16 + WG - 1) / WG), dim3(WG), 0, stream>>>(
            X, stats, gN, bN, (float*)d_out, N * 16, 1.0f / (float)N);
    }
}

// Round 4
// 435.528 us; speedup vs baseline: 6.9152x; 1.5941x over previous
//
#include <hip/hip_runtime.h>
#include <hip/hip_fp16.h>
#include <math.h>

#define WG 256

typedef _Float16 f16x8 __attribute__((ext_vector_type(8)));
typedef float    f32x4 __attribute__((ext_vector_type(4)));

__device__ __forceinline__ float gelu_f(float x) {
    return 0.5f * x * (1.0f + erff(x * 0.7071067811865476f));
}

// wave-private LDS fence: drain DS queue + compiler memory barrier
#define WAVE_LDS_FENCE() asm volatile("s_waitcnt lgkmcnt(0)" ::: "memory")

__device__ __forceinline__ void acc_h4(f32x4& s, uint2 r) {
    const __half2 ha = *(const __half2*)&r.x;
    const __half2 hb = *(const __half2*)&r.y;
    const float2 fa = __half22float2(ha);
    const float2 fb = __half22float2(hb);
    s[0] += fa.x; s[1] += fa.y; s[2] += fb.x; s[3] += fb.y;
}

// ---- K1: per-edge MLP via MFMA -> ef16[E,16], fused ELL scatter, edge-BN stats ----
// es > 0: ELL mode, slots[node*es + pos] = edge.  es == 0: CSR mode (cnt only).
__global__ __launch_bounds__(WG, 4) void edge_mlp_mfma(
    const float* __restrict__ coords,
    const float* __restrict__ normals,
    const float* __restrict__ curv,
    const int*   __restrict__ eidx,
    const float* __restrict__ W1, const float* __restrict__ b1,
    const float* __restrict__ W2, const float* __restrict__ b2,
    const float* __restrict__ W3, const float* __restrict__ b3,
    __half* __restrict__ ef16, int* __restrict__ cnt,
    int* __restrict__ slots, int es,
    float* __restrict__ stats, int E)
{
    __shared__ _Float16 h1s[4][16][72];
    __shared__ _Float16 h2s[4][16][40];
    __shared__ float red[4][32];

    const int t    = threadIdx.x;
    const int w    = t >> 6;
    const int lane = t & 63;
    const int quad = lane >> 4;
    const int col  = lane & 15;

    // ---- per-lane edge ids + early atomics (latency hidden by weight loads/MLP) ----
    const int e  = blockIdx.x * WG + w * 64 + lane;
    const bool ev = (e < E);
    const int ec = ev ? e : 0;
    const int r = eidx[ec];
    const int c = eidx[E + ec];

    int pr = 0, qc = 0;
    if (ev) {
        pr = atomicAdd(&cnt[r], 1);
        qc = atomicAdd(&cnt[c], 1);
    }

    // ---- weight B-fragments in registers ----
    f16x8 bw1[4];
#pragma unroll
    for (int n = 0; n < 4; ++n) {
#pragma unroll
        for (int j = 0; j < 8; ++j) {
            const int k = quad * 8 + j;
            bw1[n][j] = (k < 8) ? (_Float16)W1[k * 64 + n * 16 + col] : (_Float16)0.f;
        }
    }
    f16x8 bw2[2][2];
#pragma unroll
    for (int s = 0; s < 2; ++s)
#pragma unroll
        for (int n = 0; n < 2; ++n)
#pragma unroll
            for (int j = 0; j < 8; ++j)
                bw2[s][n][j] = (_Float16)W2[(s * 32 + quad * 8 + j) * 32 + n * 16 + col];
    f16x8 bw3;
#pragma unroll
    for (int j = 0; j < 8; ++j)
        bw3[j] = (_Float16)W3[(quad * 8 + j) * 16 + col];

    float b1v[4], b2v[2], b3v;
#pragma unroll
    for (int n = 0; n < 4; ++n) b1v[n] = b1[n * 16 + col];
    b2v[0] = b2[col]; b2v[1] = b2[16 + col];
    b3v = b3[col];

    // ---- geometry -> f[8] ----
    const float rx = coords[3*r], ry = coords[3*r+1], rz = coords[3*r+2];
    const float cx = coords[3*c], cy = coords[3*c+1], cz = coords[3*c+2];
    const float dx = cx - rx, dy = cy - ry, dz = cz - rz;
    const float nrx = normals[3*r], nry = normals[3*r+1], nrz = normals[3*r+2];
    const float ncx = normals[3*c], ncy = normals[3*c+1], ncz = normals[3*c+2];

    const float ndot = nrx*ncx + nry*ncy + nrz*ncz;
    const float dn   = sqrtf(dx*dx + dy*dy + dz*dz) + 1e-8f;
    const float inv  = 1.0f / dn;
    const float lo = -1.0f + 1e-8f, hi = 1.0f - 1e-8f;
    const float cr = fminf(fmaxf((nrx*dx + nry*dy + nrz*dz) * inv, lo), hi);
    const float cc2 = fminf(fmaxf((ncx*dx + ncy*dy + ncz*dz) * inv, lo), hi);
    const float cd0 = curv[4*c]   - curv[4*r];
    const float cd1 = curv[4*c+1] - curv[4*r+1];

    float f[8] = {dx, dy, dz, ndot, cr, cc2, cd0, cd1};

    // ---- ELL slot stores (scattered; overlapped with MFMA below) ----
    if (ev && es > 0) {
        if (pr < es) slots[(size_t)r * es + pr] = e;
        if (qc < es) slots[(size_t)c * es + qc] = e;
    }

    const int e0w = blockIdx.x * WG + w * 64;
    float vsum = 0.f, vsq = 0.f;

#pragma unroll
    for (int mt = 0; mt < 4; ++mt) {
        f16x8 a1;
#pragma unroll
        for (int j = 0; j < 8; ++j) {
            const float v = __shfl(f[j], (mt << 4) + col, 64);
            a1[j] = (quad == 0) ? (_Float16)v : (_Float16)0.f;
        }

        f32x4 c1[4];
#pragma unroll
        for (int n = 0; n < 4; ++n) {
            f32x4 c0 = {b1v[n], b1v[n], b1v[n], b1v[n]};
            c1[n] = __builtin_amdgcn_mfma_f32_16x16x32_f16(a1, bw1[n], c0, 0, 0, 0);
        }
#pragma unroll
        for (int n = 0; n < 4; ++n)
#pragma unroll
            for (int rg = 0; rg < 4; ++rg)
                h1s[w][quad * 4 + rg][n * 16 + col] = (_Float16)gelu_f(c1[n][rg]);

        WAVE_LDS_FENCE();

        const f16x8 a2s0 = *(const f16x8*)&h1s[w][col][quad * 8];
        const f16x8 a2s1 = *(const f16x8*)&h1s[w][col][32 + quad * 8];
        f32x4 c2[2];
#pragma unroll
        for (int n = 0; n < 2; ++n) {
            f32x4 c0 = {b2v[n], b2v[n], b2v[n], b2v[n]};
            c0 = __builtin_amdgcn_mfma_f32_16x16x32_f16(a2s0, bw2[0][n], c0, 0, 0, 0);
            c2[n] = __builtin_amdgcn_mfma_f32_16x16x32_f16(a2s1, bw2[1][n], c0, 0, 0, 0);
        }
#pragma unroll
        for (int n = 0; n < 2; ++n)
#pragma unroll
            for (int rg = 0; rg < 4; ++rg)
                h2s[w][quad * 4 + rg][n * 16 + col] = (_Float16)gelu_f(c2[n][rg]);

        WAVE_LDS_FENCE();

        const f16x8 a3 = *(const f16x8*)&h2s[w][col][quad * 8];
        f32x4 c0 = {b3v, b3v, b3v, b3v};
        const f32x4 c3 = __builtin_amdgcn_mfma_f32_16x16x32_f16(a3, bw3, c0, 0, 0, 0);

#pragma unroll
        for (int rg = 0; rg < 4; ++rg) {
            const int me = e0w + mt * 16 + quad * 4 + rg;
            if (me < E) {
                const float v = c3[rg];
                ef16[(size_t)me * 16 + col] = __float2half(v);
                vsum += v;
                vsq  += v * v;
            }
        }
    }

    vsum += __shfl_xor(vsum, 16, 64);
    vsq  += __shfl_xor(vsq,  16, 64);
    vsum += __shfl_xor(vsum, 32, 64);
    vsq  += __shfl_xor(vsq,  32, 64);
    if (lane < 16) {
        red[w][col]      = vsum;
        red[w][16 + col] = vsq;
    }
    __syncthreads();
    if (t < 32) {
        const float s = red[0][t] + red[1][t] + red[2][t] + red[3][t];
        atomicAdd(&stats[t], s);
    }
}

// ---- scan kernels (CSR fallback only) ----
__global__ __launch_bounds__(WG) void scan_blocks_kernel(
    const int* __restrict__ cnt, int* __restrict__ rowptr,
    int* __restrict__ bsum, int N)
{
    __shared__ int sd[WG];
    const int t = threadIdx.x;
    const int i = blockIdx.x * WG + t;
    const int v = (i < N) ? cnt[i] : 0;
    sd[t] = v;
    __syncthreads();
    for (int off = 1; off < WG; off <<= 1) {
        int x = 0;
        if (t >= off) x = sd[t - off];
        __syncthreads();
        sd[t] += x;
        __syncthreads();
    }
    if (i < N) rowptr[i] = sd[t] - v;
    if (t == WG - 1) bsum[blockIdx.x] = sd[t];
}

__global__ __launch_bounds__(512) void scan_top_kernel(
    const int* __restrict__ bsum, int* __restrict__ boff, int nblk)
{
    __shared__ int sd[512];
    const int t = threadIdx.x;
    const int v = (t < nblk) ? bsum[t] : 0;
    sd[t] = v;
    __syncthreads();
    for (int off = 1; off < 512; off <<= 1) {
        int x = 0;
        if (t >= off) x = sd[t - off];
        __syncthreads();
        sd[t] += x;
        __syncthreads();
    }
    if (t < nblk) boff[t] = sd[t] - v;
}

__global__ __launch_bounds__(WG) void scan_add_kernel(
    int* __restrict__ rowptr, int* __restrict__ cursor,
    const int* __restrict__ boff, int N)
{
    const int i = blockIdx.x * WG + threadIdx.x;
    if (i < N) {
        const int v = rowptr[i] + boff[blockIdx.x];
        rowptr[i] = v;
        cursor[i] = v;
    }
}

__global__ __launch_bounds__(WG) void build_kernel(
    const int* __restrict__ eidx, int* __restrict__ cursor,
    int* __restrict__ slots, int E)
{
    const int e = blockIdx.x * WG + threadIdx.x;
    if (e < E) {
        const int r = eidx[e];
        const int c = eidx[E + e];
        const int p = atomicAdd(&cursor[r], 1);
        slots[p] = e;
        const int q = atomicAdd(&cursor[c], 1);
        slots[q] = e;
    }
}

// ---- gather: 4 lanes/node, f16x4 loads + edge-BN affine + proj + node-BN stats ----
// es>0: ELL (base=node*es, cap=min(len,es)); es==0: CSR (base=rowptr[node]).
__global__ __launch_bounds__(WG) void gather_kernel(
    const __half* __restrict__ ef16, const int* __restrict__ slots,
    const int* __restrict__ rowptr, const int* __restrict__ cnt,
    const float* __restrict__ Wp, const float* __restrict__ bp,
    const float* __restrict__ gE, const float* __restrict__ bE,
    float* __restrict__ stats, float* __restrict__ X,
    int N, float invE, int es)
{
    __shared__ float sWp[256];
    __shared__ f32x4 syv[4][16][4];
    __shared__ float red2[4][32];

    const int t = threadIdx.x;
    sWp[t] = Wp[t];

    const int w    = t >> 6;
    const int lane = t & 63;
    const int g    = lane >> 2;
    const int subl = lane & 3;
    const int c0   = subl * 4;

    float a[4], bb[4], bpv[4];
#pragma unroll
    for (int cc = 0; cc < 4; ++cc) {
        const int ch = c0 + cc;
        const float mean = stats[ch] * invE;
        const float var  = stats[16 + ch] * invE - mean * mean;
        a[cc]  = gE[ch] * rsqrtf(var + 1e-5f);
        bb[cc] = bE[ch] - mean * a[cc];
        bpv[cc] = bp[ch];
    }

    const int node = blockIdx.x * 64 + w * 16 + g;

    f32x4 s = {0.f, 0.f, 0.f, 0.f};
    int len = 0;
    if (node < N) {
        len = cnt[node];
        const size_t base = (es > 0) ? (size_t)node * (size_t)es : (size_t)rowptr[node];
        const int cap = (es > 0) ? (len < es ? len : es) : len;
        const int* sl = slots + base;
        int i = 0;
        for (; i + 4 <= cap; i += 4) {
            const int e0 = sl[i], e1 = sl[i+1], e2 = sl[i+2], e3 = sl[i+3];
            const uint2 r0 = *(const uint2*)(ef16 + (size_t)e0 * 16 + c0);
            const uint2 r1 = *(const uint2*)(ef16 + (size_t)e1 * 16 + c0);
            const uint2 r2 = *(const uint2*)(ef16 + (size_t)e2 * 16 + c0);
            const uint2 r3 = *(const uint2*)(ef16 + (size_t)e3 * 16 + c0);
            acc_h4(s, r0); acc_h4(s, r1); acc_h4(s, r2); acc_h4(s, r3);
        }
        for (; i < cap; ++i) {
            const uint2 r0 = *(const uint2*)(ef16 + (size_t)sl[i] * 16 + c0);
            acc_h4(s, r0);
        }
    }

    const float d    = (float)len;
    const float invd = 1.0f / fmaxf(d, 1.0f);
    f32x4 y;
#pragma unroll
    for (int cc = 0; cc < 4; ++cc)
        y[cc] = (a[cc] * s[cc] + bb[cc] * d) * invd;

    syv[w][g][subl] = y;
    __syncthreads();   // covers sWp readiness + syv staging

    const f32x4 y0 = syv[w][g][0];
    const f32x4 y1 = syv[w][g][1];
    const f32x4 y2 = syv[w][g][2];
    const f32x4 y3 = syv[w][g][3];

    const f32x4* sWp4 = (const f32x4*)sWp;
    f32x4 x = {bpv[0], bpv[1], bpv[2], bpv[3]};
#pragma unroll
    for (int j = 0; j < 4; ++j) {
        const f32x4 wj = sWp4[j * 4 + subl];
#pragma unroll
        for (int cc = 0; cc < 4; ++cc) x[cc] += y0[j] * wj[cc];
    }
#pragma unroll
    for (int j = 0; j < 4; ++j) {
        const f32x4 wj = sWp4[(4 + j) * 4 + subl];
#pragma unroll
        for (int cc = 0; cc < 4; ++cc) x[cc] += y1[j] * wj[cc];
    }
#pragma unroll
    for (int j = 0; j < 4; ++j) {
        const f32x4 wj = sWp4[(8 + j) * 4 + subl];
#pragma unroll
        for (int cc = 0; cc < 4; ++cc) x[cc] += y2[j] * wj[cc];
    }
#pragma unroll
    for (int j = 0; j < 4; ++j) {
        const f32x4 wj = sWp4[(12 + j) * 4 + subl];
#pragma unroll
        for (int cc = 0; cc < 4; ++cc) x[cc] += y3[j] * wj[cc];
    }

    if (node < N) {
        *(f32x4*)&X[(size_t)node * 16 + c0] = x;
    } else {
        x = (f32x4){0.f, 0.f, 0.f, 0.f};
    }

    f32x4 vs = x, vq;
#pragma unroll
    for (int cc = 0; cc < 4; ++cc) vq[cc] = x[cc] * x[cc];
#pragma unroll
    for (int off = 4; off <= 32; off <<= 1) {
#pragma unroll
        for (int cc = 0; cc < 4; ++cc) {
            vs[cc] += __shfl_xor(vs[cc], off, 64);
            vq[cc] += __shfl_xor(vq[cc], off, 64);
        }
    }
    if (lane < 4) {
#pragma unroll
        for (int cc = 0; cc < 4; ++cc) {
            red2[w][c0 + cc]      = vs[cc];
            red2[w][16 + c0 + cc] = vq[cc];
        }
    }
    __syncthreads();
    if (t < 32) {
        const float ssum = red2[0][t] + red2[1][t] + red2[2][t] + red2[3][t];
        atomicAdd(&stats[32 + t], ssum);
    }
}

// ---- apply node BN (in-place when X == out) ----
__global__ __launch_bounds__(WG) void out_kernel(
    const float* __restrict__ X, const float* __restrict__ stats,
    const float* __restrict__ gN, const float* __restrict__ bN,
    float* __restrict__ out, int total, float invN)
{
    __shared__ float sA[16], sB[16];
    if (threadIdx.x < 16) {
        const int k = threadIdx.x;
        const float mean = stats[32 + k] * invN;
        const float var  = stats[48 + k] * invN - mean * mean;
        const float a    = gN[k] / sqrtf(var + 1e-5f);
        sA[k] = a;
        sB[k] = bN[k] - mean * a;
    }
    __syncthreads();
    const int i = blockIdx.x * WG + threadIdx.x;
    if (i < total) {
        out[i] = sA[i & 15] * X[i] + sB[i & 15];
    }
}

// ============================ FALLBACK (atomic) PATH ============================

__global__ __launch_bounds__(WG) void edge_kernel_fb(
    const float* __restrict__ coords,
    const float* __restrict__ normals,
    const float* __restrict__ curv,
    const int*   __restrict__ eidx,
    const float* __restrict__ W1, const float* __restrict__ b1,
    const float* __restrict__ W2, const float* __restrict__ b2,
    const float* __restrict__ W3, const float* __restrict__ b3,
    float* __restrict__ S, float* __restrict__ deg,
    float* __restrict__ stats, int E)
{
    __shared__ float sW1[512];
    __shared__ float sW2[2048];
    __shared__ float sW3[512];
    __shared__ float sB1[64];
    __shared__ float sB2[32];
    __shared__ float sB3[16];
    __shared__ float red[4][32];

    const int t = threadIdx.x;
    for (int i = t; i < 512;  i += WG) sW1[i] = W1[i];
    for (int i = t; i < 2048; i += WG) sW2[i] = W2[i];
    for (int i = t; i < 512;  i += WG) sW3[i] = W3[i];
    if (t < 64) sB1[t] = b1[t];
    if (t < 32) sB2[t] = b2[t];
    if (t < 16) sB3[t] = b3[t];
    __syncthreads();

    float vsum[16], vsq[16];
#pragma unroll
    for (int k = 0; k < 16; ++k) { vsum[k] = 0.f; vsq[k] = 0.f; }

    const int stride = gridDim.x * WG;
    for (int e = blockIdx.x * WG + t; e < E; e += stride) {
        const int r = eidx[e];
        const int c = eidx[E + e];

        const float rx = coords[3*r], ry = coords[3*r+1], rz = coords[3*r+2];
        const float cx = coords[3*c], cy = coords[3*c+1], cz = coords[3*c+2];
        const float dx = cx - rx, dy = cy - ry, dz = cz - rz;
        const float nrx = normals[3*r], nry = normals[3*r+1], nrz = normals[3*r+2];
        const float ncx = normals[3*c], ncy = normals[3*c+1], ncz = normals[3*c+2];

        const float ndot = nrx*ncx + nry*ncy + nrz*ncz;
        const float dn   = sqrtf(dx*dx + dy*dy + dz*dz) + 1e-8f;
        const float inv  = 1.0f / dn;
        const float lo = -1.0f + 1e-8f, hi = 1.0f - 1e-8f;
        const float cr = fminf(fmaxf((nrx*dx + nry*dy + nrz*dz) * inv, lo), hi);
        const float cc = fminf(fmaxf((ncx*dx + ncy*dy + ncz*dz) * inv, lo), hi);
        const float cd0 = curv[4*c]   - curv[4*r];
        const float cd1 = curv[4*c+1] - curv[4*r+1];

        const float f[8] = {dx, dy, dz, ndot, cr, cc, cd0, cd1};

        float acc2[32];
#pragma unroll
        for (int j = 0; j < 32; ++j) acc2[j] = sB2[j];
        for (int i = 0; i < 64; ++i) {
            float a = sB1[i];
#pragma unroll
            for (int k = 0; k < 8; ++k) a += f[k] * sW1[k*64 + i];
            const float g = gelu_f(a);
#pragma unroll
            for (int j = 0; j < 32; ++j) acc2[j] += g * sW2[i*32 + j];
        }
        float ef[16];
#pragma unroll
        for (int k = 0; k < 16; ++k) ef[k] = sB3[k];
#pragma unroll
        for (int i = 0; i < 32; ++i) {
            const float g = gelu_f(acc2[i]);
#pragma unroll
            for (int k = 0; k < 16; ++k) ef[k] += g * sW3[i*16 + k];
        }

#pragma unroll
        for (int k = 0; k < 16; ++k) {
            atomicAdd(&S[16*(size_t)r + k], ef[k]);
            atomicAdd(&S[16*(size_t)c + k], ef[k]);
            vsum[k] += ef[k];
            vsq[k]  += ef[k] * ef[k];
        }
        atomicAdd(&deg[r], 1.0f);
        atomicAdd(&deg[c], 1.0f);
    }

#pragma unroll
    for (int k = 0; k < 16; ++k) {
        float a = vsum[k], b = vsq[k];
#pragma unroll
        for (int off = 32; off > 0; off >>= 1) {
            a += __shfl_down(a, off);
            b += __shfl_down(b, off);
        }
        vsum[k] = a; vsq[k] = b;
    }
    const int wave = t >> 6;
    if ((t & 63) == 0) {
#pragma unroll
        for (int k = 0; k < 16; ++k) {
            red[wave][k]      = vsum[k];
            red[wave][16 + k] = vsq[k];
        }
    }
    __syncthreads();
    if (t < 32) {
        const float s = red[0][t] + red[1][t] + red[2][t] + red[3][t];
        atomicAdd(&stats[t], s);
    }
}

__global__ __launch_bounds__(WG) void node_kernel_fb(
    const float* __restrict__ S, const float* __restrict__ deg,
    const float* __restrict__ Wp, const float* __restrict__ bp,
    const float* __restrict__ gE, const float* __restrict__ bE,
    float* __restrict__ X, float* __restrict__ stats,
    int N, float invE)
{
    __shared__ float sWp[256];
    __shared__ float sBp[16];
    __shared__ float sA[16], sB[16];
    __shared__ float red[4][32];

    const int t = threadIdx.x;
    sWp[t] = Wp[t & 255];
    if (t < 16) {
        sBp[t] = bp[t];
        const float mean = stats[t] * invE;
        const float var  = stats[16 + t] * invE - mean * mean;
        const float a    = gE[t] / sqrtf(var + 1e-5f);
        sA[t] = a;
        sB[t] = bE[t] - mean * a;
    }
    __syncthreads();

    const int n = blockIdx.x * WG + t;
    float x[16];
#pragma unroll
    for (int k = 0; k < 16; ++k) x[k] = 0.f;

    if (n < N) {
        const float d    = deg[n];
        const float invd = 1.0f / fmaxf(d, 1.0f);
        float y[16];
#pragma unroll
        for (int k = 0; k < 16; ++k)
            y[k] = (sA[k] * S[16*(size_t)n + k] + sB[k] * d) * invd;
#pragma unroll
        for (int k = 0; k < 16; ++k) x[k] = sBp[k];
#pragma unroll
        for (int j = 0; j < 16; ++j) {
            const float yj = y[j];
#pragma unroll
            for (int k = 0; k < 16; ++k) x[k] += yj * sWp[j*16 + k];
        }
#pragma unroll
        for (int k = 0; k < 16; ++k) X[16*(size_t)n + k] = x[k];
    }

    float vs[16], vq[16];
#pragma unroll
    for (int k = 0; k < 16; ++k) { vs[k] = x[k]; vq[k] = x[k]*x[k]; }
#pragma unroll
    for (int k = 0; k < 16; ++k) {
        float a = vs[k], b = vq[k];
#pragma unroll
        for (int off = 32; off > 0; off >>= 1) {
            a += __shfl_down(a, off);
            b += __shfl_down(b, off);
        }
        vs[k] = a; vq[k] = b;
    }
    const int wave = t >> 6;
    if ((t & 63) == 0) {
#pragma unroll
        for (int k = 0; k < 16; ++k) {
            red[wave][k]      = vs[k];
            red[wave][16 + k] = vq[k];
        }
    }
    __syncthreads();
    if (t < 32) {
        const float s = red[0][t] + red[1][t] + red[2][t] + red[3][t];
        atomicAdd(&stats[32 + t], s);
    }
}

// ============================ LAUNCH ============================

extern "C" void kernel_launch(void* const* d_in, const int* in_sizes, int n_in,
                              void* d_out, int out_size, void* d_ws, size_t ws_size,
                              hipStream_t stream)
{
    const float* coords  = (const float*)d_in[0];
    const float* normals = (const float*)d_in[1];
    const float* curv    = (const float*)d_in[2];
    const int*   eidx    = (const int*)d_in[3];
    const float* W1 = (const float*)d_in[4];
    const float* b1 = (const float*)d_in[5];
    const float* W2 = (const float*)d_in[6];
    const float* b2 = (const float*)d_in[7];
    const float* W3 = (const float*)d_in[8];
    const float* b3 = (const float*)d_in[9];
    const float* gE = (const float*)d_in[10];
    const float* bE = (const float*)d_in[11];
    const float* Wp = (const float*)d_in[12];
    const float* bp = (const float*)d_in[13];
    const float* gN = (const float*)d_in[14];
    const float* bN = (const float*)d_in[15];

    const int N = in_sizes[0] / 3;
    const int E = in_sizes[3] / 2;
    const int eblk = (E + WG - 1) / WG;
    const int nblk = (N + WG - 1) / WG;
    float* out = (float*)d_out;

    // ---------- try ELL path: stats[64] | cnt[N] | slots[N*es] | ef16[E*16] ----------
    const size_t off_cnt   = 256;
    const size_t cnt_bytes = (((size_t)N * 4) + 255) & ~(size_t)255;
    const size_t off_slots = off_cnt + cnt_bytes;
    const size_t ef_bytes  = (size_t)E * 32;

    int es = 0;
    const int strides[3] = {96, 80, 64};
    for (int si = 0; si < 3; ++si) {
        const size_t need = off_slots + (size_t)N * (size_t)strides[si] * 4 + ef_bytes;
        if (need <= ws_size) { es = strides[si]; break; }
    }

    if (es > 0) {
        float*  stats = (float*)d_ws;
        int*    cnt   = (int*)((char*)d_ws + off_cnt);
        int*    slots = (int*)((char*)d_ws + off_slots);
        __half* ef16  = (__half*)((char*)d_ws + off_slots + (size_t)N * (size_t)es * 4);

        hipMemsetAsync(d_ws, 0, off_cnt + (size_t)N * 4, stream);

        edge_mlp_mfma<<<dim3(eblk), dim3(WG), 0, stream>>>(
            coords, normals, curv, eidx, W1, b1, W2, b2, W3, b3,
            ef16, cnt, slots, es, stats, E);

        gather_kernel<<<dim3((N + 63) / 64), dim3(WG), 0, stream>>>(
            ef16, slots, /*rowptr*/cnt, cnt, Wp, bp, gE, bE, stats, out,
            N, 1.0f / (float)E, es);

        out_kernel<<<dim3((N * 16 + WG - 1) / WG), dim3(WG), 0, stream>>>(
            out, stats, gN, bN, out, N * 16, 1.0f / (float)N);
        return;
    }

    // ---------- CSR path: stats|cnt|rowptr|cursor|bsum|boff|slots2E|ef16 ----------
    const size_t need_csr = (size_t)(64 + 3 * (size_t)N + 8192 + 2 * (size_t)E) * 4
                          + ef_bytes + 256;
    if (ws_size >= need_csr && nblk <= 4096) {
        float*  stats  = (float*)d_ws;
        int*    cnt    = (int*)(stats + 64);
        int*    rowptr = cnt + N;
        int*    cursor = rowptr + N;
        int*    bsum   = cursor + N;
        int*    boff   = bsum + 4096;
        int*    slots  = boff + 4096;
        __half* ef16   = (__half*)(slots + 2 * (size_t)E);

        hipMemsetAsync(d_ws, 0, (size_t)(64 + N) * 4, stream);

        edge_mlp_mfma<<<dim3(eblk), dim3(WG), 0, stream>>>(
            coords, normals, curv, eidx, W1, b1, W2, b2, W3, b3,
            ef16, cnt, slots, 0, stats, E);

        scan_blocks_kernel<<<dim3(nblk), dim3(WG), 0, stream>>>(cnt, rowptr, bsum, N);
        scan_top_kernel<<<dim3(1), dim3(512), 0, stream>>>(bsum, boff, nblk);
        scan_add_kernel<<<dim3(nblk), dim3(WG), 0, stream>>>(rowptr, cursor, boff, N);
        build_kernel<<<dim3(eblk), dim3(WG), 0, stream>>>(eidx, cursor, slots, E);

        gather_kernel<<<dim3((N + 63) / 64), dim3(WG), 0, stream>>>(
            ef16, slots, rowptr, cnt, Wp, bp, gE, bE, stats, out,
            N, 1.0f / (float)E, 0);

        out_kernel<<<dim3((N * 16 + WG - 1) / WG), dim3(WG), 0, stream>>>(
            out, stats, gN, bN, out, N * 16, 1.0f / (float)N);
        return;
    }

    // ---------- last-resort atomic path ----------
    {
        float* S     = (float*)d_ws;
        float* deg   = S + (size_t)N * 16;
        float* stats = deg + N;
        float* X     = stats + 64;

        hipMemsetAsync(d_ws, 0, ((size_t)N * 16 + N + 64) * sizeof(float), stream);

        edge_kernel_fb<<<dim3(2048), dim3(WG), 0, stream>>>(
            coords, normals, curv, eidx, W1, b1, W2, b2, W3, b3,
            S, deg, stats, E);

        node_kernel_fb<<<dim3(nblk), dim3(WG), 0, stream>>>(
            S, deg, Wp, bp, gE, bE, X, stats, N, 1.0f / (float)E);

        out_kernel<<<dim3((N * 16 + WG - 1) / WG), dim3(WG), 0, stream>>>(
            X, stats, gN, bN, out, N * 16, 1.0f / (float)N);
    }
}

// Round 5
// 383.309 us; speedup vs baseline: 7.8572x; 1.1362x over previous
//
#include <hip/hip_runtime.h>
#include <hip/hip_fp16.h>
#include <math.h>

#define WG 256

typedef _Float16 f16x8 __attribute__((ext_vector_type(8)));
typedef float    f32x4 __attribute__((ext_vector_type(4)));

// tanh-form GELU (max |err| vs exact erf-GELU ~3e-3), branchless, ~13 VALU.
__device__ __forceinline__ float gelu_f(float x) {
    float u = 0.7978845608028654f * x * fmaf(0.044715f * x, x, 1.0f);
    u = fminf(fmaxf(u, -9.0f), 9.0f);
    const float e = __expf(2.0f * u);
    return 0.5f * x * (1.0f + __fdividef(e - 1.0f, e + 1.0f));
}

// wave-private LDS fence: drain DS queue + compiler memory barrier
#define WAVE_LDS_FENCE() asm volatile("s_waitcnt lgkmcnt(0)" ::: "memory")

__device__ __forceinline__ void acc_h4(f32x4& s, uint2 r) {
    const __half2 ha = *(const __half2*)&r.x;
    const __half2 hb = *(const __half2*)&r.y;
    const float2 fa = __half22float2(ha);
    const float2 fb = __half22float2(hb);
    s[0] += fa.x; s[1] += fa.y; s[2] += fb.x; s[3] += fb.y;
}

// ---- K1: per-edge MLP via MFMA; three output modes ----
// mode 2: slot-order ELL — write edge row directly to both endpoints' ELL rows.
// mode 1: ELL slots    — ef16[e] sequential + slots[node*es+pos]=e.
// mode 0: CSR          — ef16[e] sequential + cnt only.
__global__ __launch_bounds__(WG, 4) void edge_mlp_mfma(
    const float* __restrict__ coords,
    const float* __restrict__ normals,
    const float* __restrict__ curv,
    const int*   __restrict__ eidx,
    const float* __restrict__ W1, const float* __restrict__ b1,
    const float* __restrict__ W2, const float* __restrict__ b2,
    const float* __restrict__ W3, const float* __restrict__ b3,
    __half* __restrict__ ef16, int* __restrict__ cnt,
    int* __restrict__ slots, _Float16* __restrict__ ellA,
    int es, int mode,
    float* __restrict__ stats, int E)
{
    __shared__ _Float16 h1s[4][16][72];
    __shared__ _Float16 h2s[4][16][40];
    __shared__ float red[4][32];

    const int t    = threadIdx.x;
    const int w    = t >> 6;
    const int lane = t & 63;
    const int quad = lane >> 4;
    const int col  = lane & 15;

    // ---- per-lane edge ids + early atomics ----
    const int e  = blockIdx.x * WG + w * 64 + lane;
    const bool ev = (e < E);
    const int ec = ev ? e : 0;
    const int r = eidx[ec];
    const int c = eidx[E + ec];

    int pr = 0, qc = 0;
    if (ev) {
        pr = atomicAdd(&cnt[r], 1);
        qc = atomicAdd(&cnt[c], 1);
    }
    // packed ELL destinations (row index), -1 = invalid
    const int packR = (ev && pr < es) ? r * es + pr : -1;
    const int packC = (ev && qc < es) ? c * es + qc : -1;

    // ---- weight B-fragments in registers ----
    f16x8 bw1[4];
#pragma unroll
    for (int n = 0; n < 4; ++n) {
#pragma unroll
        for (int j = 0; j < 8; ++j) {
            const int k = quad * 8 + j;
            bw1[n][j] = (k < 8) ? (_Float16)W1[k * 64 + n * 16 + col] : (_Float16)0.f;
        }
    }
    f16x8 bw2[2][2];
#pragma unroll
    for (int s = 0; s < 2; ++s)
#pragma unroll
        for (int n = 0; n < 2; ++n)
#pragma unroll
            for (int j = 0; j < 8; ++j)
                bw2[s][n][j] = (_Float16)W2[(s * 32 + quad * 8 + j) * 32 + n * 16 + col];
    f16x8 bw3;
#pragma unroll
    for (int j = 0; j < 8; ++j)
        bw3[j] = (_Float16)W3[(quad * 8 + j) * 16 + col];

    float b1v[4], b2v[2], b3v;
#pragma unroll
    for (int n = 0; n < 4; ++n) b1v[n] = b1[n * 16 + col];
    b2v[0] = b2[col]; b2v[1] = b2[16 + col];
    b3v = b3[col];

    // ---- geometry -> f[8] ----
    const float rx = coords[3*r], ry = coords[3*r+1], rz = coords[3*r+2];
    const float cx = coords[3*c], cy = coords[3*c+1], cz = coords[3*c+2];
    const float dx = cx - rx, dy = cy - ry, dz = cz - rz;
    const float nrx = normals[3*r], nry = normals[3*r+1], nrz = normals[3*r+2];
    const float ncx = normals[3*c], ncy = normals[3*c+1], ncz = normals[3*c+2];

    const float ndot = nrx*ncx + nry*ncy + nrz*ncz;
    const float dn   = sqrtf(dx*dx + dy*dy + dz*dz) + 1e-8f;
    const float inv  = 1.0f / dn;
    const float lo = -1.0f + 1e-8f, hi = 1.0f - 1e-8f;
    const float cr = fminf(fmaxf((nrx*dx + nry*dy + nrz*dz) * inv, lo), hi);
    const float cc2 = fminf(fmaxf((ncx*dx + ncy*dy + ncz*dz) * inv, lo), hi);
    const float cd0 = curv[4*c]   - curv[4*r];
    const float cd1 = curv[4*c+1] - curv[4*r+1];

    float f[8] = {dx, dy, dz, ndot, cr, cc2, cd0, cd1};

    // ---- mode-1 slot stores ----
    if (mode == 1 && ev) {
        if (pr < es) slots[(size_t)r * es + pr] = e;
        if (qc < es) slots[(size_t)c * es + qc] = e;
    }

    const int e0w = blockIdx.x * WG + w * 64;
    float vsum = 0.f, vsq = 0.f;

#pragma unroll
    for (int mt = 0; mt < 4; ++mt) {
        f16x8 a1;
#pragma unroll
        for (int j = 0; j < 8; ++j) {
            const float v = __shfl(f[j], (mt << 4) + col, 64);
            a1[j] = (quad == 0) ? (_Float16)v : (_Float16)0.f;
        }

        f32x4 c1[4];
#pragma unroll
        for (int n = 0; n < 4; ++n) {
            f32x4 c0 = {b1v[n], b1v[n], b1v[n], b1v[n]};
            c1[n] = __builtin_amdgcn_mfma_f32_16x16x32_f16(a1, bw1[n], c0, 0, 0, 0);
        }
#pragma unroll
        for (int n = 0; n < 4; ++n)
#pragma unroll
            for (int rg = 0; rg < 4; ++rg)
                h1s[w][quad * 4 + rg][n * 16 + col] = (_Float16)gelu_f(c1[n][rg]);

        WAVE_LDS_FENCE();

        const f16x8 a2s0 = *(const f16x8*)&h1s[w][col][quad * 8];
        const f16x8 a2s1 = *(const f16x8*)&h1s[w][col][32 + quad * 8];
        f32x4 c2[2];
#pragma unroll
        for (int n = 0; n < 2; ++n) {
            f32x4 c0 = {b2v[n], b2v[n], b2v[n], b2v[n]};
            c0 = __builtin_amdgcn_mfma_f32_16x16x32_f16(a2s0, bw2[0][n], c0, 0, 0, 0);
            c2[n] = __builtin_amdgcn_mfma_f32_16x16x32_f16(a2s1, bw2[1][n], c0, 0, 0, 0);
        }
#pragma unroll
        for (int n = 0; n < 2; ++n)
#pragma unroll
            for (int rg = 0; rg < 4; ++rg)
                h2s[w][quad * 4 + rg][n * 16 + col] = (_Float16)gelu_f(c2[n][rg]);

        WAVE_LDS_FENCE();

        const f16x8 a3 = *(const f16x8*)&h2s[w][col][quad * 8];
        f32x4 c0 = {b3v, b3v, b3v, b3v};
        const f32x4 c3 = __builtin_amdgcn_mfma_f32_16x16x32_f16(a3, bw3, c0, 0, 0, 0);

        // edge-BN stats from the accumulator (col fixed per lane)
#pragma unroll
        for (int rg = 0; rg < 4; ++rg) {
            const int me = e0w + mt * 16 + quad * 4 + rg;
            if (me < E) {
                const float v = c3[rg];
                vsum += v;
                vsq  += v * v;
            }
        }

        if (mode == 2) {
            // transpose c3 through h2s (a3 reads already drained by in-order DS
            // + fence) so 4-lane groups own full 32B edge rows, then scatter
            // both endpoint rows directly.
            WAVE_LDS_FENCE();
#pragma unroll
            for (int rg = 0; rg < 4; ++rg)
                h2s[w][quad * 4 + rg][col] = (_Float16)c3[rg];
            WAVE_LDS_FENCE();
            const int j    = lane >> 2;
            const int subl = lane & 3;
            const uint2 v = *(const uint2*)&h2s[w][j][subl * 4];
            const int srcl = (mt << 4) + j;
            const int dR = __shfl(packR, srcl, 64);
            const int dC = __shfl(packC, srcl, 64);
            if (dR >= 0) *(uint2*)((char*)ellA + (size_t)dR * 32 + subl * 8) = v;
            if (dC >= 0) *(uint2*)((char*)ellA + (size_t)dC * 32 + subl * 8) = v;
        } else {
            // sequential ef16[e] store
#pragma unroll
            for (int rg = 0; rg < 4; ++rg) {
                const int me = e0w + mt * 16 + quad * 4 + rg;
                if (me < E) ef16[(size_t)me * 16 + col] = __float2half(c3[rg]);
            }
        }
    }

    vsum += __shfl_xor(vsum, 16, 64);
    vsq  += __shfl_xor(vsq,  16, 64);
    vsum += __shfl_xor(vsum, 32, 64);
    vsq  += __shfl_xor(vsq,  32, 64);
    if (lane < 16) {
        red[w][col]      = vsum;
        red[w][16 + col] = vsq;
    }
    __syncthreads();
    if (t < 32) {
        const float s = red[0][t] + red[1][t] + red[2][t] + red[3][t];
        atomicAdd(&stats[t], s);
    }
}

// ---- gather for slot-order ELL: sequential per-node rows ----
__global__ __launch_bounds__(WG) void gather_seq_kernel(
    const _Float16* __restrict__ ellA, const int* __restrict__ cnt,
    const float* __restrict__ Wp, const float* __restrict__ bp,
    const float* __restrict__ gE, const float* __restrict__ bE,
    float* __restrict__ stats, float* __restrict__ X,
    int N, float invE, int es)
{
    __shared__ float sWp[256];
    __shared__ f32x4 syv[4][16][4];
    __shared__ float red2[4][32];

    const int t = threadIdx.x;
    sWp[t] = Wp[t];

    const int w    = t >> 6;
    const int lane = t & 63;
    const int g    = lane >> 2;
    const int subl = lane & 3;
    const int c0   = subl * 4;

    float a[4], bb[4], bpv[4];
#pragma unroll
    for (int cc = 0; cc < 4; ++cc) {
        const int ch = c0 + cc;
        const float mean = stats[ch] * invE;
        const float var  = stats[16 + ch] * invE - mean * mean;
        a[cc]  = gE[ch] * rsqrtf(var + 1e-5f);
        bb[cc] = bE[ch] - mean * a[cc];
        bpv[cc] = bp[ch];
    }

    const int node = blockIdx.x * 64 + w * 16 + g;

    f32x4 s = {0.f, 0.f, 0.f, 0.f};
    int len = 0;
    if (node < N) {
        len = cnt[node];
        const int cap = len < es ? len : es;
        const char* base = (const char*)ellA + (size_t)node * es * 32 + subl * 8;
        int i = 0;
        for (; i + 4 <= cap; i += 4) {
            const uint2 r0 = *(const uint2*)(base + (size_t)(i    ) * 32);
            const uint2 r1 = *(const uint2*)(base + (size_t)(i + 1) * 32);
            const uint2 r2 = *(const uint2*)(base + (size_t)(i + 2) * 32);
            const uint2 r3 = *(const uint2*)(base + (size_t)(i + 3) * 32);
            acc_h4(s, r0); acc_h4(s, r1); acc_h4(s, r2); acc_h4(s, r3);
        }
        for (; i < cap; ++i) {
            const uint2 r0 = *(const uint2*)(base + (size_t)i * 32);
            acc_h4(s, r0);
        }
    }

    const float d    = (float)len;
    const float invd = 1.0f / fmaxf(d, 1.0f);
    f32x4 y;
#pragma unroll
    for (int cc = 0; cc < 4; ++cc)
        y[cc] = (a[cc] * s[cc] + bb[cc] * d) * invd;

    syv[w][g][subl] = y;
    __syncthreads();

    const f32x4 y0 = syv[w][g][0];
    const f32x4 y1 = syv[w][g][1];
    const f32x4 y2 = syv[w][g][2];
    const f32x4 y3 = syv[w][g][3];

    const f32x4* sWp4 = (const f32x4*)sWp;
    f32x4 x = {bpv[0], bpv[1], bpv[2], bpv[3]};
#pragma unroll
    for (int j = 0; j < 4; ++j) {
        const f32x4 wj = sWp4[j * 4 + subl];
#pragma unroll
        for (int cc = 0; cc < 4; ++cc) x[cc] += y0[j] * wj[cc];
    }
#pragma unroll
    for (int j = 0; j < 4; ++j) {
        const f32x4 wj = sWp4[(4 + j) * 4 + subl];
#pragma unroll
        for (int cc = 0; cc < 4; ++cc) x[cc] += y1[j] * wj[cc];
    }
#pragma unroll
    for (int j = 0; j < 4; ++j) {
        const f32x4 wj = sWp4[(8 + j) * 4 + subl];
#pragma unroll
        for (int cc = 0; cc < 4; ++cc) x[cc] += y2[j] * wj[cc];
    }
#pragma unroll
    for (int j = 0; j < 4; ++j) {
        const f32x4 wj = sWp4[(12 + j) * 4 + subl];
#pragma unroll
        for (int cc = 0; cc < 4; ++cc) x[cc] += y3[j] * wj[cc];
    }

    if (node < N) {
        *(f32x4*)&X[(size_t)node * 16 + c0] = x;
    } else {
        x = (f32x4){0.f, 0.f, 0.f, 0.f};
    }

    f32x4 vs = x, vq;
#pragma unroll
    for (int cc = 0; cc < 4; ++cc) vq[cc] = x[cc] * x[cc];
#pragma unroll
    for (int off = 4; off <= 32; off <<= 1) {
#pragma unroll
        for (int cc = 0; cc < 4; ++cc) {
            vs[cc] += __shfl_xor(vs[cc], off, 64);
            vq[cc] += __shfl_xor(vq[cc], off, 64);
        }
    }
    if (lane < 4) {
#pragma unroll
        for (int cc = 0; cc < 4; ++cc) {
            red2[w][c0 + cc]      = vs[cc];
            red2[w][16 + c0 + cc] = vq[cc];
        }
    }
    __syncthreads();
    if (t < 32) {
        const float ssum = red2[0][t] + red2[1][t] + red2[2][t] + red2[3][t];
        atomicAdd(&stats[32 + t], ssum);
    }
}

// ---- scan kernels (CSR fallback only) ----
__global__ __launch_bounds__(WG) void scan_blocks_kernel(
    const int* __restrict__ cnt, int* __restrict__ rowptr,
    int* __restrict__ bsum, int N)
{
    __shared__ int sd[WG];
    const int t = threadIdx.x;
    const int i = blockIdx.x * WG + t;
    const int v = (i < N) ? cnt[i] : 0;
    sd[t] = v;
    __syncthreads();
    for (int off = 1; off < WG; off <<= 1) {
        int x = 0;
        if (t >= off) x = sd[t - off];
        __syncthreads();
        sd[t] += x;
        __syncthreads();
    }
    if (i < N) rowptr[i] = sd[t] - v;
    if (t == WG - 1) bsum[blockIdx.x] = sd[t];
}

__global__ __launch_bounds__(512) void scan_top_kernel(
    const int* __restrict__ bsum, int* __restrict__ boff, int nblk)
{
    __shared__ int sd[512];
    const int t = threadIdx.x;
    const int v = (t < nblk) ? bsum[t] : 0;
    sd[t] = v;
    __syncthreads();
    for (int off = 1; off < 512; off <<= 1) {
        int x = 0;
        if (t >= off) x = sd[t - off];
        __syncthreads();
        sd[t] += x;
        __syncthreads();
    }
    if (t < nblk) boff[t] = sd[t] - v;
}

__global__ __launch_bounds__(WG) void scan_add_kernel(
    int* __restrict__ rowptr, int* __restrict__ cursor,
    const int* __restrict__ boff, int N)
{
    const int i = blockIdx.x * WG + threadIdx.x;
    if (i < N) {
        const int v = rowptr[i] + boff[blockIdx.x];
        rowptr[i] = v;
        cursor[i] = v;
    }
}

__global__ __launch_bounds__(WG) void build_kernel(
    const int* __restrict__ eidx, int* __restrict__ cursor,
    int* __restrict__ slots, int E)
{
    const int e = blockIdx.x * WG + threadIdx.x;
    if (e < E) {
        const int r = eidx[e];
        const int c = eidx[E + e];
        const int p = atomicAdd(&cursor[r], 1);
        slots[p] = e;
        const int q = atomicAdd(&cursor[c], 1);
        slots[q] = e;
    }
}

// ---- gather via slots indirection (ELL-slots / CSR fallback) ----
__global__ __launch_bounds__(WG) void gather_kernel(
    const __half* __restrict__ ef16, const int* __restrict__ slots,
    const int* __restrict__ rowptr, const int* __restrict__ cnt,
    const float* __restrict__ Wp, const float* __restrict__ bp,
    const float* __restrict__ gE, const float* __restrict__ bE,
    float* __restrict__ stats, float* __restrict__ X,
    int N, float invE, int es)
{
    __shared__ float sWp[256];
    __shared__ f32x4 syv[4][16][4];
    __shared__ float red2[4][32];

    const int t = threadIdx.x;
    sWp[t] = Wp[t];

    const int w    = t >> 6;
    const int lane = t & 63;
    const int g    = lane >> 2;
    const int subl = lane & 3;
    const int c0   = subl * 4;

    float a[4], bb[4], bpv[4];
#pragma unroll
    for (int cc = 0; cc < 4; ++cc) {
        const int ch = c0 + cc;
        const float mean = stats[ch] * invE;
        const float var  = stats[16 + ch] * invE - mean * mean;
        a[cc]  = gE[ch] * rsqrtf(var + 1e-5f);
        bb[cc] = bE[ch] - mean * a[cc];
        bpv[cc] = bp[ch];
    }

    const int node = blockIdx.x * 64 + w * 16 + g;

    f32x4 s = {0.f, 0.f, 0.f, 0.f};
    int len = 0;
    if (node < N) {
        len = cnt[node];
        const size_t base = (es > 0) ? (size_t)node * (size_t)es : (size_t)rowptr[node];
        const int cap = (es > 0) ? (len < es ? len : es) : len;
        const int* sl = slots + base;
        int i = 0;
        for (; i + 4 <= cap; i += 4) {
            const int e0 = sl[i], e1 = sl[i+1], e2 = sl[i+2], e3 = sl[i+3];
            const uint2 r0 = *(const uint2*)(ef16 + (size_t)e0 * 16 + c0);
            const uint2 r1 = *(const uint2*)(ef16 + (size_t)e1 * 16 + c0);
            const uint2 r2 = *(const uint2*)(ef16 + (size_t)e2 * 16 + c0);
            const uint2 r3 = *(const uint2*)(ef16 + (size_t)e3 * 16 + c0);
            acc_h4(s, r0); acc_h4(s, r1); acc_h4(s, r2); acc_h4(s, r3);
        }
        for (; i < cap; ++i) {
            const uint2 r0 = *(const uint2*)(ef16 + (size_t)sl[i] * 16 + c0);
            acc_h4(s, r0);
        }
    }

    const float d    = (float)len;
    const float invd = 1.0f / fmaxf(d, 1.0f);
    f32x4 y;
#pragma unroll
    for (int cc = 0; cc < 4; ++cc)
        y[cc] = (a[cc] * s[cc] + bb[cc] * d) * invd;

    syv[w][g][subl] = y;
    __syncthreads();

    const f32x4 y0 = syv[w][g][0];
    const f32x4 y1 = syv[w][g][1];
    const f32x4 y2 = syv[w][g][2];
    const f32x4 y3 = syv[w][g][3];

    const f32x4* sWp4 = (const f32x4*)sWp;
    f32x4 x = {bpv[0], bpv[1], bpv[2], bpv[3]};
#pragma unroll
    for (int j = 0; j < 4; ++j) {
        const f32x4 wj = sWp4[j * 4 + subl];
#pragma unroll
        for (int cc = 0; cc < 4; ++cc) x[cc] += y0[j] * wj[cc];
    }
#pragma unroll
    for (int j = 0; j < 4; ++j) {
        const f32x4 wj = sWp4[(4 + j) * 4 + subl];
#pragma unroll
        for (int cc = 0; cc < 4; ++cc) x[cc] += y1[j] * wj[cc];
    }
#pragma unroll
    for (int j = 0; j < 4; ++j) {
        const f32x4 wj = sWp4[(8 + j) * 4 + subl];
#pragma unroll
        for (int cc = 0; cc < 4; ++cc) x[cc] += y2[j] * wj[cc];
    }
#pragma unroll
    for (int j = 0; j < 4; ++j) {
        const f32x4 wj = sWp4[(12 + j) * 4 + subl];
#pragma unroll
        for (int cc = 0; cc < 4; ++cc) x[cc] += y3[j] * wj[cc];
    }

    if (node < N) {
        *(f32x4*)&X[(size_t)node * 16 + c0] = x;
    } else {
        x = (f32x4){0.f, 0.f, 0.f, 0.f};
    }

    f32x4 vs = x, vq;
#pragma unroll
    for (int cc = 0; cc < 4; ++cc) vq[cc] = x[cc] * x[cc];
#pragma unroll
    for (int off = 4; off <= 32; off <<= 1) {
#pragma unroll
        for (int cc = 0; cc < 4; ++cc) {
            vs[cc] += __shfl_xor(vs[cc], off, 64);
            vq[cc] += __shfl_xor(vq[cc], off, 64);
        }
    }
    if (lane < 4) {
#pragma unroll
        for (int cc = 0; cc < 4; ++cc) {
            red2[w][c0 + cc]      = vs[cc];
            red2[w][16 + c0 + cc] = vq[cc];
        }
    }
    __syncthreads();
    if (t < 32) {
        const float ssum = red2[0][t] + red2[1][t] + red2[2][t] + red2[3][t];
        atomicAdd(&stats[32 + t], ssum);
    }
}

// ---- apply node BN (in-place when X == out) ----
__global__ __launch_bounds__(WG) void out_kernel(
    const float* __restrict__ X, const float* __restrict__ stats,
    const float* __restrict__ gN, const float* __restrict__ bN,
    float* __restrict__ out, int total, float invN)
{
    __shared__ float sA[16], sB[16];
    if (threadIdx.x < 16) {
        const int k = threadIdx.x;
        const float mean = stats[32 + k] * invN;
        const float var  = stats[48 + k] * invN - mean * mean;
        const float a    = gN[k] / sqrtf(var + 1e-5f);
        sA[k] = a;
        sB[k] = bN[k] - mean * a;
    }
    __syncthreads();
    const int i = blockIdx.x * WG + threadIdx.x;
    if (i < total) {
        out[i] = sA[i & 15] * X[i] + sB[i & 15];
    }
}

// ============================ LAUNCH ============================

extern "C" void kernel_launch(void* const* d_in, const int* in_sizes, int n_in,
                              void* d_out, int out_size, void* d_ws, size_t ws_size,
                              hipStream_t stream)
{
    const float* coords  = (const float*)d_in[0];
    const float* normals = (const float*)d_in[1];
    const float* curv    = (const float*)d_in[2];
    const int*   eidx    = (const int*)d_in[3];
    const float* W1 = (const float*)d_in[4];
    const float* b1 = (const float*)d_in[5];
    const float* W2 = (const float*)d_in[6];
    const float* b2 = (const float*)d_in[7];
    const float* W3 = (const float*)d_in[8];
    const float* b3 = (const float*)d_in[9];
    const float* gE = (const float*)d_in[10];
    const float* bE = (const float*)d_in[11];
    const float* Wp = (const float*)d_in[12];
    const float* bp = (const float*)d_in[13];
    const float* gN = (const float*)d_in[14];
    const float* bN = (const float*)d_in[15];

    const int N = in_sizes[0] / 3;
    const int E = in_sizes[3] / 2;
    const int eblk = (E + WG - 1) / WG;
    const int nblk = (N + WG - 1) / WG;
    float* out = (float*)d_out;

    const size_t off_cnt   = 256;
    const size_t cnt_bytes = (((size_t)N * 4) + 255) & ~(size_t)255;
    const size_t ef_bytes  = (size_t)E * 32;

    // ---------- slot-order ELL: stats | cnt | ellA[N*64 rows x 32B] ----------
    {
        const int es = 64;
        const size_t need_so = off_cnt + cnt_bytes + (size_t)N * (size_t)es * 32;
        if (ws_size >= need_so) {
            float*    stats = (float*)d_ws;
            int*      cnt   = (int*)((char*)d_ws + off_cnt);
            _Float16* ellA  = (_Float16*)((char*)d_ws + off_cnt + cnt_bytes);

            hipMemsetAsync(d_ws, 0, off_cnt + (size_t)N * 4, stream);

            edge_mlp_mfma<<<dim3(eblk), dim3(WG), 0, stream>>>(
                coords, normals, curv, eidx, W1, b1, W2, b2, W3, b3,
                (__half*)nullptr, cnt, (int*)nullptr, ellA, es, /*mode*/2, stats, E);

            gather_seq_kernel<<<dim3((N + 63) / 64), dim3(WG), 0, stream>>>(
                ellA, cnt, Wp, bp, gE, bE, stats, out, N, 1.0f / (float)E, es);

            out_kernel<<<dim3((N * 16 + WG - 1) / WG), dim3(WG), 0, stream>>>(
                out, stats, gN, bN, out, N * 16, 1.0f / (float)N);
            return;
        }
    }

    // ---------- ELL-slots (round-4 path): stats | cnt | slots[N*es] | ef16 ----------
    {
        const size_t off_slots = off_cnt + cnt_bytes;
        int es = 0;
        const int strides[3] = {96, 80, 64};
        for (int si = 0; si < 3; ++si) {
            const size_t need = off_slots + (size_t)N * (size_t)strides[si] * 4 + ef_bytes;
            if (need <= ws_size) { es = strides[si]; break; }
        }
        if (es > 0) {
            float*  stats = (float*)d_ws;
            int*    cnt   = (int*)((char*)d_ws + off_cnt);
            int*    slots = (int*)((char*)d_ws + off_slots);
            __half* ef16  = (__half*)((char*)d_ws + off_slots + (size_t)N * (size_t)es * 4);

            hipMemsetAsync(d_ws, 0, off_cnt + (size_t)N * 4, stream);

            edge_mlp_mfma<<<dim3(eblk), dim3(WG), 0, stream>>>(
                coords, normals, curv, eidx, W1, b1, W2, b2, W3, b3,
                ef16, cnt, slots, (_Float16*)nullptr, es, /*mode*/1, stats, E);

            gather_kernel<<<dim3((N + 63) / 64), dim3(WG), 0, stream>>>(
                ef16, slots, cnt, cnt, Wp, bp, gE, bE, stats, out,
                N, 1.0f / (float)E, es);

            out_kernel<<<dim3((N * 16 + WG - 1) / WG), dim3(WG), 0, stream>>>(
                out, stats, gN, bN, out, N * 16, 1.0f / (float)N);
            return;
        }
    }

    // ---------- CSR path ----------
    const size_t need_csr = (size_t)(64 + 3 * (size_t)N + 8192 + 2 * (size_t)E) * 4
                          + ef_bytes + 256;
    if (ws_size >= need_csr && nblk <= 4096) {
        float*  stats  = (float*)d_ws;
        int*    cnt    = (int*)(stats + 64);
        int*    rowptr = cnt + N;
        int*    cursor = rowptr + N;
        int*    bsum   = cursor + N;
        int*    boff   = bsum + 4096;
        int*    slots  = boff + 4096;
        __half* ef16   = (__half*)(slots + 2 * (size_t)E);

        hipMemsetAsync(d_ws, 0, (size_t)(64 + N) * 4, stream);

        edge_mlp_mfma<<<dim3(eblk), dim3(WG), 0, stream>>>(
            coords, normals, curv, eidx, W1, b1, W2, b2, W3, b3,
            ef16, cnt, slots, (_Float16*)nullptr, 0, /*mode*/0, stats, E);

        scan_blocks_kernel<<<dim3(nblk), dim3(WG), 0, stream>>>(cnt, rowptr, bsum, N);
        scan_top_kernel<<<dim3(1), dim3(512), 0, stream>>>(bsum, boff, nblk);
        scan_add_kernel<<<dim3(nblk), dim3(WG), 0, stream>>>(rowptr, cursor, boff, N);
        build_kernel<<<dim3(eblk), dim3(WG), 0, stream>>>(eidx, cursor, slots, E);

        gather_kernel<<<dim3((N + 63) / 64), dim3(WG), 0, stream>>>(
            ef16, slots, rowptr, cnt, Wp, bp, gE, bE, stats, out,
            N, 1.0f / (float)E, 0);

        out_kernel<<<dim3((N * 16 + WG - 1) / WG), dim3(WG), 0, stream>>>(
            out, stats, gN, bN, out, N * 16, 1.0f / (float)N);
        return;
    }
}

// Round 7
// 371.680 us; speedup vs baseline: 8.1031x; 1.0313x over previous
//
#include <hip/hip_runtime.h>
#include <hip/hip_fp16.h>
#include <math.h>

#define WG 256

typedef _Float16 f16x8 __attribute__((ext_vector_type(8)));
typedef float    f32x4 __attribute__((ext_vector_type(4)));

// scalar tanh-form GELU (fallback kernels)
__device__ __forceinline__ float gelu_f(float x) {
    float u = 0.7978845608028654f * x * fmaf(0.044715f * x, x, 1.0f);
    u = fminf(fmaxf(u, -9.0f), 9.0f);
    const float e = __expf(2.0f * u);
    return 0.5f * x * (1.0f + __fdividef(e - 1.0f, e + 1.0f));
}

// pair GELU: polynomial+clamp in f32, exp/ratio in packed f16.
// u clamped to +-4.2 so exp(2u) <= exp(8.4)=4447 stays in f16 range;
// tanh(4.2)=1 within ~5e-4. Max |err| vs exact erf-GELU ~3e-3.
__device__ __forceinline__ __half2 gelu2(float xa, float xb) {
    float ua = 0.7978845608f * xa * fmaf(0.044715f * xa, xa, 1.0f);
    float ub = 0.7978845608f * xb * fmaf(0.044715f * xb, xb, 1.0f);
    ua = fminf(fmaxf(ua, -4.2f), 4.2f);
    ub = fminf(fmaxf(ub, -4.2f), 4.2f);
    const __half2 e   = h2exp(__float22half2_rn(make_float2(2.0f * ua, 2.0f * ub)));
    const __half2 one = __float2half2_rn(1.0f);
    const __half2 t   = __hmul2(__hsub2(e, one), h2rcp(__hadd2(e, one)));
    const float2  tf  = __half22float2(t);
    return __float22half2_rn(make_float2(0.5f * xa * (1.0f + tf.x),
                                         0.5f * xb * (1.0f + tf.y)));
}

// wave-private LDS fence: drain DS queue + compiler memory barrier
#define WAVE_LDS_FENCE() asm volatile("s_waitcnt lgkmcnt(0)" ::: "memory")

__device__ __forceinline__ void acc_h4(f32x4& s, uint2 r) {
    const __half2 ha = *(const __half2*)&r.x;
    const __half2 hb = *(const __half2*)&r.y;
    const float2 fa = __half22float2(ha);
    const float2 fb = __half22float2(hb);
    s[0] += fa.x; s[1] += fa.y; s[2] += fb.x; s[3] += fb.y;
}

// ---- K1: per-edge MLP via MFMA; phase-restructured (6 fences/wave) ----
// mode 2: slot-order ELL — write edge row directly to both endpoints' ELL rows.
// mode 1: ELL slots    — ef16[e] sequential + slots[node*es+pos]=e.
// mode 0: CSR          — ef16[e] sequential + cnt only.
__global__ __launch_bounds__(WG, 4) void edge_mlp_mfma(
    const float* __restrict__ coords,
    const float* __restrict__ normals,
    const float* __restrict__ curv,
    const int*   __restrict__ eidx,
    const float* __restrict__ W1, const float* __restrict__ b1,
    const float* __restrict__ W2, const float* __restrict__ b2,
    const float* __restrict__ W3, const float* __restrict__ b3,
    __half* __restrict__ ef16, int* __restrict__ cnt,
    int* __restrict__ slots, _Float16* __restrict__ ellA,
    int es, int mode,
    float* __restrict__ stats, int E)
{
    // per-wave staging for a PAIR of 16-edge tiles (32 rows)
    __shared__ __half h1s[4][32][68];   // layer-1 acts; later reused as c3 transpose buf
    __shared__ __half h2s[4][32][36];   // layer-2 acts
    __shared__ float red[4][32];

    const int t    = threadIdx.x;
    const int w    = t >> 6;
    const int lane = t & 63;
    const int quad = lane >> 4;
    const int col  = lane & 15;

    // ---- per-lane edge ids + early atomics ----
    const int e  = blockIdx.x * WG + w * 64 + lane;
    const bool ev = (e < E);
    const int ec = ev ? e : 0;
    const int r = eidx[ec];
    const int c = eidx[E + ec];

    int pr = 0, qc = 0;
    if (ev) {
        pr = atomicAdd(&cnt[r], 1);
        qc = atomicAdd(&cnt[c], 1);
    }
    const int packR = (ev && pr < es) ? r * es + pr : -1;
    const int packC = (ev && qc < es) ? c * es + qc : -1;

    // ---- weight B-fragments in registers ----
    f16x8 bw1[4];
#pragma unroll
    for (int n = 0; n < 4; ++n) {
#pragma unroll
        for (int j = 0; j < 8; ++j) {
            const int k = quad * 8 + j;
            bw1[n][j] = (k < 8) ? (_Float16)W1[k * 64 + n * 16 + col] : (_Float16)0.f;
        }
    }
    f16x8 bw2[2][2];
#pragma unroll
    for (int s = 0; s < 2; ++s)
#pragma unroll
        for (int n = 0; n < 2; ++n)
#pragma unroll
            for (int j = 0; j < 8; ++j)
                bw2[s][n][j] = (_Float16)W2[(s * 32 + quad * 8 + j) * 32 + n * 16 + col];
    f16x8 bw3;
#pragma unroll
    for (int j = 0; j < 8; ++j)
        bw3[j] = (_Float16)W3[(quad * 8 + j) * 16 + col];

    float b1v[4], b2v[2], b3v;
#pragma unroll
    for (int n = 0; n < 4; ++n) b1v[n] = b1[n * 16 + col];
    b2v[0] = b2[col]; b2v[1] = b2[16 + col];
    b3v = b3[col];

    // ---- geometry -> f[8] ----
    const float rx = coords[3*r], ry = coords[3*r+1], rz = coords[3*r+2];
    const float cx = coords[3*c], cy = coords[3*c+1], cz = coords[3*c+2];
    const float dx = cx - rx, dy = cy - ry, dz = cz - rz;
    const float nrx = normals[3*r], nry = normals[3*r+1], nrz = normals[3*r+2];
    const float ncx = normals[3*c], ncy = normals[3*c+1], ncz = normals[3*c+2];

    const float ndot = nrx*ncx + nry*ncy + nrz*ncz;
    const float dn   = sqrtf(dx*dx + dy*dy + dz*dz) + 1e-8f;
    const float inv  = 1.0f / dn;
    const float lo = -1.0f + 1e-8f, hi = 1.0f - 1e-8f;
    const float cr = fminf(fmaxf((nrx*dx + nry*dy + nrz*dz) * inv, lo), hi);
    const float cc2 = fminf(fmaxf((ncx*dx + ncy*dy + ncz*dz) * inv, lo), hi);
    const float cd0 = curv[4*c]   - curv[4*r];
    const float cd1 = curv[4*c+1] - curv[4*r+1];

    float f[8] = {dx, dy, dz, ndot, cr, cc2, cd0, cd1};

    // ---- mode-1 slot stores ----
    if (mode == 1 && ev) {
        if (pr < es) slots[(size_t)r * es + pr] = e;
        if (qc < es) slots[(size_t)c * es + qc] = e;
    }

    const int e0w = blockIdx.x * WG + w * 64;
    float vsum = 0.f, vsq = 0.f;

#pragma unroll
    for (int p = 0; p < 2; ++p) {
        // ======== phase 1: layer-1 for tiles mt=2p, 2p+1 ========
#pragma unroll
        for (int mtl = 0; mtl < 2; ++mtl) {
            const int mt = 2 * p + mtl;
            f16x8 a1;
#pragma unroll
            for (int j = 0; j < 8; ++j) {
                const float v = __shfl(f[j], (mt << 4) + col, 64);
                a1[j] = (quad == 0) ? (_Float16)v : (_Float16)0.f;
            }
            f32x4 c1[4];
#pragma unroll
            for (int n = 0; n < 4; ++n) {
                f32x4 c0 = {b1v[n], b1v[n], b1v[n], b1v[n]};
                c1[n] = __builtin_amdgcn_mfma_f32_16x16x32_f16(a1, bw1[n], c0, 0, 0, 0);
            }
            // packed GELU over n-pairs (cols np*32+col and np*32+col+16)
#pragma unroll
            for (int np = 0; np < 2; ++np)
#pragma unroll
                for (int rg = 0; rg < 4; ++rg) {
                    const __half2 g = gelu2(c1[2*np][rg], c1[2*np+1][rg]);
                    __half* dst = &h1s[w][mtl*16 + quad*4 + rg][np*32 + col];
                    dst[0]  = __low2half(g);
                    dst[16] = __high2half(g);
                }
        }
        WAVE_LDS_FENCE();

        // ======== phase 2: layer-2 (both tiles, independent chains) ========
        f32x4 c2s[2][2];
#pragma unroll
        for (int mtl = 0; mtl < 2; ++mtl) {
            const f16x8 a2s0 = *(const f16x8*)&h1s[w][mtl*16 + col][quad * 8];
            const f16x8 a2s1 = *(const f16x8*)&h1s[w][mtl*16 + col][32 + quad * 8];
#pragma unroll
            for (int n = 0; n < 2; ++n) {
                f32x4 c0 = {b2v[n], b2v[n], b2v[n], b2v[n]};
                c0 = __builtin_amdgcn_mfma_f32_16x16x32_f16(a2s0, bw2[0][n], c0, 0, 0, 0);
                c2s[mtl][n] = __builtin_amdgcn_mfma_f32_16x16x32_f16(a2s1, bw2[1][n], c0, 0, 0, 0);
            }
        }
#pragma unroll
        for (int mtl = 0; mtl < 2; ++mtl)
#pragma unroll
            for (int rg = 0; rg < 4; ++rg) {
                const __half2 g = gelu2(c2s[mtl][0][rg], c2s[mtl][1][rg]);
                __half* dst = &h2s[w][mtl*16 + quad*4 + rg][col];
                dst[0]  = __low2half(g);
                dst[16] = __high2half(g);
            }
        WAVE_LDS_FENCE();

        // ======== phase 3: layer-3 + output ========
#pragma unroll
        for (int mtl = 0; mtl < 2; ++mtl) {
            const int mt = 2 * p + mtl;
            const f16x8 a3 = *(const f16x8*)&h2s[w][mtl*16 + col][quad * 8];
            f32x4 c0 = {b3v, b3v, b3v, b3v};
            const f32x4 c3 = __builtin_amdgcn_mfma_f32_16x16x32_f16(a3, bw3, c0, 0, 0, 0);

#pragma unroll
            for (int rg = 0; rg < 4; ++rg) {
                const int me = e0w + mt * 16 + quad * 4 + rg;
                if (me < E) { vsum += c3[rg]; vsq += c3[rg] * c3[rg]; }
            }

            if (mode == 2) {
                // transpose staging into (dead) h1s region, cols 0..15
#pragma unroll
                for (int rg = 0; rg < 4; ++rg)
                    h1s[w][mtl*16 + quad*4 + rg][col] = __float2half(c3[rg]);
            } else {
#pragma unroll
                for (int rg = 0; rg < 4; ++rg) {
                    const int me = e0w + mt * 16 + quad * 4 + rg;
                    if (me < E) ef16[(size_t)me * 16 + col] = __float2half(c3[rg]);
                }
            }
        }

        if (mode == 2) {
            WAVE_LDS_FENCE();
            const int j    = lane >> 2;
            const int subl = lane & 3;
#pragma unroll
            for (int mtl = 0; mtl < 2; ++mtl) {
                const int mt = 2 * p + mtl;
                const uint2 v = *(const uint2*)&h1s[w][mtl*16 + j][subl * 4];
                const int srcl = (mt << 4) + j;
                const int dR = __shfl(packR, srcl, 64);
                const int dC = __shfl(packC, srcl, 64);
                if (dR >= 0) *(uint2*)((char*)ellA + (size_t)dR * 32 + subl * 8) = v;
                if (dC >= 0) *(uint2*)((char*)ellA + (size_t)dC * 32 + subl * 8) = v;
            }
        }
    }

    vsum += __shfl_xor(vsum, 16, 64);
    vsq  += __shfl_xor(vsq,  16, 64);
    vsum += __shfl_xor(vsum, 32, 64);
    vsq  += __shfl_xor(vsq,  32, 64);
    if (lane < 16) {
        red[w][col]      = vsum;
        red[w][16 + col] = vsq;
    }
    __syncthreads();
    if (t < 32) {
        const float s = red[0][t] + red[1][t] + red[2][t] + red[3][t];
        atomicAdd(&stats[t], s);
    }
}

// ---- gather for slot-order ELL: sequential per-node rows ----
__global__ __launch_bounds__(WG) void gather_seq_kernel(
    const _Float16* __restrict__ ellA, const int* __restrict__ cnt,
    const float* __restrict__ Wp, const float* __restrict__ bp,
    const float* __restrict__ gE, const float* __restrict__ bE,
    float* __restrict__ stats, float* __restrict__ X,
    int N, float invE, int es)
{
    __shared__ float sWp[256];
    __shared__ f32x4 syv[4][16][4];
    __shared__ float red2[4][32];

    const int t = threadIdx.x;
    sWp[t] = Wp[t];

    const int w    = t >> 6;
    const int lane = t & 63;
    const int g    = lane >> 2;
    const int subl = lane & 3;
    const int c0   = subl * 4;

    float a[4], bb[4], bpv[4];
#pragma unroll
    for (int cc = 0; cc < 4; ++cc) {
        const int ch = c0 + cc;
        const float mean = stats[ch] * invE;
        const float var  = stats[16 + ch] * invE - mean * mean;
        a[cc]  = gE[ch] * rsqrtf(var + 1e-5f);
        bb[cc] = bE[ch] - mean * a[cc];
        bpv[cc] = bp[ch];
    }

    const int node = blockIdx.x * 64 + w * 16 + g;

    f32x4 s = {0.f, 0.f, 0.f, 0.f};
    int len = 0;
    if (node < N) {
        len = cnt[node];
        const int cap = len < es ? len : es;
        const char* base = (const char*)ellA + (size_t)node * es * 32 + subl * 8;
        int i = 0;
        for (; i + 4 <= cap; i += 4) {
            const uint2 r0 = *(const uint2*)(base + (size_t)(i    ) * 32);
            const uint2 r1 = *(const uint2*)(base + (size_t)(i + 1) * 32);
            const uint2 r2 = *(const uint2*)(base + (size_t)(i + 2) * 32);
            const uint2 r3 = *(const uint2*)(base + (size_t)(i + 3) * 32);
            acc_h4(s, r0); acc_h4(s, r1); acc_h4(s, r2); acc_h4(s, r3);
        }
        for (; i < cap; ++i) {
            const uint2 r0 = *(const uint2*)(base + (size_t)i * 32);
            acc_h4(s, r0);
        }
    }

    const float d    = (float)len;
    const float invd = 1.0f / fmaxf(d, 1.0f);
    f32x4 y;
#pragma unroll
    for (int cc = 0; cc < 4; ++cc)
        y[cc] = (a[cc] * s[cc] + bb[cc] * d) * invd;

    syv[w][g][subl] = y;
    __syncthreads();

    const f32x4 y0 = syv[w][g][0];
    const f32x4 y1 = syv[w][g][1];
    const f32x4 y2 = syv[w][g][2];
    const f32x4 y3 = syv[w][g][3];

    const f32x4* sWp4 = (const f32x4*)sWp;
    f32x4 x = {bpv[0], bpv[1], bpv[2], bpv[3]};
#pragma unroll
    for (int j = 0; j < 4; ++j) {
        const f32x4 wj = sWp4[j * 4 + subl];
#pragma unroll
        for (int cc = 0; cc < 4; ++cc) x[cc] += y0[j] * wj[cc];
    }
#pragma unroll
    for (int j = 0; j < 4; ++j) {
        const f32x4 wj = sWp4[(4 + j) * 4 + subl];
#pragma unroll
        for (int cc = 0; cc < 4; ++cc) x[cc] += y1[j] * wj[cc];
    }
#pragma unroll
    for (int j = 0; j < 4; ++j) {
        const f32x4 wj = sWp4[(8 + j) * 4 + subl];
#pragma unroll
        for (int cc = 0; cc < 4; ++cc) x[cc] += y2[j] * wj[cc];
    }
#pragma unroll
    for (int j = 0; j < 4; ++j) {
        const f32x4 wj = sWp4[(12 + j) * 4 + subl];
#pragma unroll
        for (int cc = 0; cc < 4; ++cc) x[cc] += y3[j] * wj[cc];
    }

    if (node < N) {
        *(f32x4*)&X[(size_t)node * 16 + c0] = x;
    } else {
        x = (f32x4){0.f, 0.f, 0.f, 0.f};
    }

    f32x4 vs = x, vq;
#pragma unroll
    for (int cc = 0; cc < 4; ++cc) vq[cc] = x[cc] * x[cc];
#pragma unroll
    for (int off = 4; off <= 32; off <<= 1) {
#pragma unroll
        for (int cc = 0; cc < 4; ++cc) {
            vs[cc] += __shfl_xor(vs[cc], off, 64);
            vq[cc] += __shfl_xor(vq[cc], off, 64);
        }
    }
    if (lane < 4) {
#pragma unroll
        for (int cc = 0; cc < 4; ++cc) {
            red2[w][c0 + cc]      = vs[cc];
            red2[w][16 + c0 + cc] = vq[cc];
        }
    }
    __syncthreads();
    if (t < 32) {
        const float ssum = red2[0][t] + red2[1][t] + red2[2][t] + red2[3][t];
        atomicAdd(&stats[32 + t], ssum);
    }
}

// ---- scan kernels (CSR fallback only) ----
__global__ __launch_bounds__(WG) void scan_blocks_kernel(
    const int* __restrict__ cnt, int* __restrict__ rowptr,
    int* __restrict__ bsum, int N)
{
    __shared__ int sd[WG];
    const int t = threadIdx.x;
    const int i = blockIdx.x * WG + t;
    const int v = (i < N) ? cnt[i] : 0;
    sd[t] = v;
    __syncthreads();
    for (int off = 1; off < WG; off <<= 1) {
        int x = 0;
        if (t >= off) x = sd[t - off];
        __syncthreads();
        sd[t] += x;
        __syncthreads();
    }
    if (i < N) rowptr[i] = sd[t] - v;
    if (t == WG - 1) bsum[blockIdx.x] = sd[t];
}

__global__ __launch_bounds__(512) void scan_top_kernel(
    const int* __restrict__ bsum, int* __restrict__ boff, int nblk)
{
    __shared__ int sd[512];
    const int t = threadIdx.x;
    const int v = (t < nblk) ? bsum[t] : 0;
    sd[t] = v;
    __syncthreads();
    for (int off = 1; off < 512; off <<= 1) {
        int x = 0;
        if (t >= off) x = sd[t - off];
        __syncthreads();
        sd[t] += x;
        __syncthreads();
    }
    if (t < nblk) boff[t] = sd[t] - v;
}

__global__ __launch_bounds__(WG) void scan_add_kernel(
    int* __restrict__ rowptr, int* __restrict__ cursor,
    const int* __restrict__ boff, int N)
{
    const int i = blockIdx.x * WG + threadIdx.x;
    if (i < N) {
        const int v = rowptr[i] + boff[blockIdx.x];
        rowptr[i] = v;
        cursor[i] = v;
    }
}

__global__ __launch_bounds__(WG) void build_kernel(
    const int* __restrict__ eidx, int* __restrict__ cursor,
    int* __restrict__ slots, int E)
{
    const int e = blockIdx.x * WG + threadIdx.x;
    if (e < E) {
        const int r = eidx[e];
        const int c = eidx[E + e];
        const int p = atomicAdd(&cursor[r], 1);
        slots[p] = e;
        const int q = atomicAdd(&cursor[c], 1);
        slots[q] = e;
    }
}

// ---- gather via slots indirection (ELL-slots / CSR fallback) ----
__global__ __launch_bounds__(WG) void gather_kernel(
    const __half* __restrict__ ef16, const int* __restrict__ slots,
    const int* __restrict__ rowptr, const int* __restrict__ cnt,
    const float* __restrict__ Wp, const float* __restrict__ bp,
    const float* __restrict__ gE, const float* __restrict__ bE,
    float* __restrict__ stats, float* __restrict__ X,
    int N, float invE, int es)
{
    __shared__ float sWp[256];
    __shared__ f32x4 syv[4][16][4];
    __shared__ float red2[4][32];

    const int t = threadIdx.x;
    sWp[t] = Wp[t];

    const int w    = t >> 6;
    const int lane = t & 63;
    const int g    = lane >> 2;
    const int subl = lane & 3;
    const int c0   = subl * 4;

    float a[4], bb[4], bpv[4];
#pragma unroll
    for (int cc = 0; cc < 4; ++cc) {
        const int ch = c0 + cc;
        const float mean = stats[ch] * invE;
        const float var  = stats[16 + ch] * invE - mean * mean;
        a[cc]  = gE[ch] * rsqrtf(var + 1e-5f);
        bb[cc] = bE[ch] - mean * a[cc];
        bpv[cc] = bp[ch];
    }

    const int node = blockIdx.x * 64 + w * 16 + g;

    f32x4 s = {0.f, 0.f, 0.f, 0.f};
    int len = 0;
    if (node < N) {
        len = cnt[node];
        const size_t base = (es > 0) ? (size_t)node * (size_t)es : (size_t)rowptr[node];
        const int cap = (es > 0) ? (len < es ? len : es) : len;
        const int* sl = slots + base;
        int i = 0;
        for (; i + 4 <= cap; i += 4) {
            const int e0 = sl[i], e1 = sl[i+1], e2 = sl[i+2], e3 = sl[i+3];
            const uint2 r0 = *(const uint2*)(ef16 + (size_t)e0 * 16 + c0);
            const uint2 r1 = *(const uint2*)(ef16 + (size_t)e1 * 16 + c0);
            const uint2 r2 = *(const uint2*)(ef16 + (size_t)e2 * 16 + c0);
            const uint2 r3 = *(const uint2*)(ef16 + (size_t)e3 * 16 + c0);
            acc_h4(s, r0); acc_h4(s, r1); acc_h4(s, r2); acc_h4(s, r3);
        }
        for (; i < cap; ++i) {
            const uint2 r0 = *(const uint2*)(ef16 + (size_t)sl[i] * 16 + c0);
            acc_h4(s, r0);
        }
    }

    const float d    = (float)len;
    const float invd = 1.0f / fmaxf(d, 1.0f);
    f32x4 y;
#pragma unroll
    for (int cc = 0; cc < 4; ++cc)
        y[cc] = (a[cc] * s[cc] + bb[cc] * d) * invd;

    syv[w][g][subl] = y;
    __syncthreads();

    const f32x4 y0 = syv[w][g][0];
    const f32x4 y1 = syv[w][g][1];
    const f32x4 y2 = syv[w][g][2];
    const f32x4 y3 = syv[w][g][3];

    const f32x4* sWp4 = (const f32x4*)sWp;
    f32x4 x = {bpv[0], bpv[1], bpv[2], bpv[3]};
#pragma unroll
    for (int j = 0; j < 4; ++j) {
        const f32x4 wj = sWp4[j * 4 + subl];
#pragma unroll
        for (int cc = 0; cc < 4; ++cc) x[cc] += y0[j] * wj[cc];
    }
#pragma unroll
    for (int j = 0; j < 4; ++j) {
        const f32x4 wj = sWp4[(4 + j) * 4 + subl];
#pragma unroll
        for (int cc = 0; cc < 4; ++cc) x[cc] += y1[j] * wj[cc];
    }
#pragma unroll
    for (int j = 0; j < 4; ++j) {
        const f32x4 wj = sWp4[(8 + j) * 4 + subl];
#pragma unroll
        for (int cc = 0; cc < 4; ++cc) x[cc] += y2[j] * wj[cc];
    }
#pragma unroll
    for (int j = 0; j < 4; ++j) {
        const f32x4 wj = sWp4[(12 + j) * 4 + subl];
#pragma unroll
        for (int cc = 0; cc < 4; ++cc) x[cc] += y3[j] * wj[cc];
    }

    if (node < N) {
        *(f32x4*)&X[(size_t)node * 16 + c0] = x;
    } else {
        x = (f32x4){0.f, 0.f, 0.f, 0.f};
    }

    f32x4 vs = x, vq;
#pragma unroll
    for (int cc = 0; cc < 4; ++cc) vq[cc] = x[cc] * x[cc];
#pragma unroll
    for (int off = 4; off <= 32; off <<= 1) {
#pragma unroll
        for (int cc = 0; cc < 4; ++cc) {
            vs[cc] += __shfl_xor(vs[cc], off, 64);
            vq[cc] += __shfl_xor(vq[cc], off, 64);
        }
    }
    if (lane < 4) {
#pragma unroll
        for (int cc = 0; cc < 4; ++cc) {
            red2[w][c0 + cc]      = vs[cc];
            red2[w][16 + c0 + cc] = vq[cc];
        }
    }
    __syncthreads();
    if (t < 32) {
        const float ssum = red2[0][t] + red2[1][t] + red2[2][t] + red2[3][t];
        atomicAdd(&stats[32 + t], ssum);
    }
}

// ---- apply node BN (in-place when X == out) ----
__global__ __launch_bounds__(WG) void out_kernel(
    const float* __restrict__ X, const float* __restrict__ stats,
    const float* __restrict__ gN, const float* __restrict__ bN,
    float* __restrict__ out, int total, float invN)
{
    __shared__ float sA[16], sB[16];
    if (threadIdx.x < 16) {
        const int k = threadIdx.x;
        const float mean = stats[32 + k] * invN;
        const float var  = stats[48 + k] * invN - mean * mean;
        const float a    = gN[k] / sqrtf(var + 1e-5f);
        sA[k] = a;
        sB[k] = bN[k] - mean * a;
    }
    __syncthreads();
    const int i = blockIdx.x * WG + threadIdx.x;
    if (i < total) {
        out[i] = sA[i & 15] * X[i] + sB[i & 15];
    }
}

// ============================ LAUNCH ============================

extern "C" void kernel_launch(void* const* d_in, const int* in_sizes, int n_in,
                              void* d_out, int out_size, void* d_ws, size_t ws_size,
                              hipStream_t stream)
{
    const float* coords  = (const float*)d_in[0];
    const float* normals = (const float*)d_in[1];
    const float* curv    = (const float*)d_in[2];
    const int*   eidx    = (const int*)d_in[3];
    const float* W1 = (const float*)d_in[4];
    const float* b1 = (const float*)d_in[5];
    const float* W2 = (const float*)d_in[6];
    const float* b2 = (const float*)d_in[7];
    const float* W3 = (const float*)d_in[8];
    const float* b3 = (const float*)d_in[9];
    const float* gE = (const float*)d_in[10];
    const float* bE = (const float*)d_in[11];
    const float* Wp = (const float*)d_in[12];
    const float* bp = (const float*)d_in[13];
    const float* gN = (const float*)d_in[14];
    const float* bN = (const float*)d_in[15];

    const int N = in_sizes[0] / 3;
    const int E = in_sizes[3] / 2;
    const int eblk = (E + WG - 1) / WG;
    const int nblk = (N + WG - 1) / WG;
    float* out = (float*)d_out;

    const size_t off_cnt   = 256;
    const size_t cnt_bytes = (((size_t)N * 4) + 255) & ~(size_t)255;
    const size_t ef_bytes  = (size_t)E * 32;

    // ---------- slot-order ELL: stats | cnt | ellA[N*64 rows x 32B] ----------
    {
        const int es = 64;
        const size_t need_so = off_cnt + cnt_bytes + (size_t)N * (size_t)es * 32;
        if (ws_size >= need_so) {
            float*    stats = (float*)d_ws;
            int*      cnt   = (int*)((char*)d_ws + off_cnt);
            _Float16* ellA  = (_Float16*)((char*)d_ws + off_cnt + cnt_bytes);

            hipMemsetAsync(d_ws, 0, off_cnt + (size_t)N * 4, stream);

            edge_mlp_mfma<<<dim3(eblk), dim3(WG), 0, stream>>>(
                coords, normals, curv, eidx, W1, b1, W2, b2, W3, b3,
                (__half*)nullptr, cnt, (int*)nullptr, ellA, es, /*mode*/2, stats, E);

            gather_seq_kernel<<<dim3((N + 63) / 64), dim3(WG), 0, stream>>>(
                ellA, cnt, Wp, bp, gE, bE, stats, out, N, 1.0f / (float)E, es);

            out_kernel<<<dim3((N * 16 + WG - 1) / WG), dim3(WG), 0, stream>>>(
                out, stats, gN, bN, out, N * 16, 1.0f / (float)N);
            return;
        }
    }

    // ---------- ELL-slots: stats | cnt | slots[N*es] | ef16 ----------
    {
        const size_t off_slots = off_cnt + cnt_bytes;
        int es = 0;
        const int strides[3] = {96, 80, 64};
        for (int si = 0; si < 3; ++si) {
            const size_t need = off_slots + (size_t)N * (size_t)strides[si] * 4 + ef_bytes;
            if (need <= ws_size) { es = strides[si]; break; }
        }
        if (es > 0) {
            float*  stats = (float*)d_ws;
            int*    cnt   = (int*)((char*)d_ws + off_cnt);
            int*    slots = (int*)((char*)d_ws + off_slots);
            __half* ef16  = (__half*)((char*)d_ws + off_slots + (size_t)N * (size_t)es * 4);

            hipMemsetAsync(d_ws, 0, off_cnt + (size_t)N * 4, stream);

            edge_mlp_mfma<<<dim3(eblk), dim3(WG), 0, stream>>>(
                coords, normals, curv, eidx, W1, b1, W2, b2, W3, b3,
                ef16, cnt, slots, (_Float16*)nullptr, es, /*mode*/1, stats, E);

            gather_kernel<<<dim3((N + 63) / 64), dim3(WG), 0, stream>>>(
                ef16, slots, cnt, cnt, Wp, bp, gE, bE, stats, out,
                N, 1.0f / (float)E, es);

            out_kernel<<<dim3((N * 16 + WG - 1) / WG), dim3(WG), 0, stream>>>(
                out, stats, gN, bN, out, N * 16, 1.0f / (float)N);
            return;
        }
    }

    // ---------- CSR path ----------
    const size_t need_csr = (size_t)(64 + 3 * (size_t)N + 8192 + 2 * (size_t)E) * 4
                          + ef_bytes + 256;
    if (ws_size >= need_csr && nblk <= 4096) {
        float*  stats  = (float*)d_ws;
        int*    cnt    = (int*)(stats + 64);
        int*    rowptr = cnt + N;
        int*    cursor = rowptr + N;
        int*    bsum   = cursor + N;
        int*    boff   = bsum + 4096;
        int*    slots  = boff + 4096;
        __half* ef16   = (__half*)(slots + 2 * (size_t)E);

        hipMemsetAsync(d_ws, 0, (size_t)(64 + N) * 4, stream);

        edge_mlp_mfma<<<dim3(eblk), dim3(WG), 0, stream>>>(
            coords, normals, curv, eidx, W1, b1, W2, b2, W3, b3,
            ef16, cnt, slots, (_Float16*)nullptr, 0, /*mode*/0, stats, E);

        scan_blocks_kernel<<<dim3(nblk), dim3(WG), 0, stream>>>(cnt, rowptr, bsum, N);
        scan_top_kernel<<<dim3(1), dim3(512), 0, stream>>>(bsum, boff, nblk);
        scan_add_kernel<<<dim3(nblk), dim3(WG), 0, stream>>>(rowptr, cursor, boff, N);
        build_kernel<<<dim3(eblk), dim3(WG), 0, stream>>>(eidx, cursor, slots, E);

        gather_kernel<<<dim3((N + 63) / 64), dim3(WG), 0, stream>>>(
            ef16, slots, rowptr, cnt, Wp, bp, gE, bE, stats, out,
            N, 1.0f / (float)E, 0);

        out_kernel<<<dim3((N * 16 + WG - 1) / WG), dim3(WG), 0, stream>>>(
            out, stats, gN, bN, out, N * 16, 1.0f / (float)N);
        return;
    }
}